// Round 8
// baseline (903.611 us; speedup 1.0000x reference)
//
#include <hip/hip_runtime.h>
#include <math.h>

// ---------------------------------------------------------------------------
// NTSNet forward. Big GEMMs on MFMA via 2-way f16 split (3 products: hh,hl,lh)
// R2: parallel means. R3: split-K. R4: 2-phase dbuf + XCD swizzle. R5: fused
// prep. R6: A direct global->VGPR (REGRESSED: same-iter dependent loads).
// R7: A-fragments software-pipelined in REGISTERS (2-deep, consumed next
//     phase) + B LDS-dbuf; split-K=3 backbone (624 blocks, all resident @3/CU).
// ---------------------------------------------------------------------------

typedef _Float16 h8 __attribute__((ext_vector_type(8)));
typedef float f32x4 __attribute__((ext_vector_type(4)));

#define ASCALE 256.0f
#define WSCALE 16384.0f
#define RSCALE (1.0f / (256.0f * 16384.0f))
#define PSLAB ((size_t)1664 * 2048)

__device__ __forceinline__ void gload16(const void* g, void* l) {
  __builtin_amdgcn_global_load_lds(
      (__attribute__((address_space(1))) void*)(void*)(uintptr_t)g,
      (__attribute__((address_space(3))) void*)l, 16, 0, 0);
}

// ---------------- merged small prep: anchors + w2/w3 permutes ---------------
__device__ void anchors_body(int i, int* anch, float* areas) {
  if (i >= 1614) return;
  int stride, oh, a, pos;
  double size, sc;
  const double C13 = 1.2599210498948732;
  const double C23 = 1.5874010519681994;
  if (i < 1176) {
    stride = 32; size = 48.0; oh = 14; a = i / 196; pos = i % 196;
    sc = (a / 3 == 0) ? C13 : C23;
  } else if (i < 1470) {
    int r = i - 1176; stride = 64; size = 96.0; oh = 7; a = r / 49; pos = r % 49;
    sc = (a / 3 == 0) ? C13 : C23;
  } else {
    int r = i - 1470; stride = 128; size = 192.0; oh = 4; a = r / 16; pos = r % 16;
    int si = a / 3;
    sc = (si == 0) ? 1.0 : ((si == 1) ? C13 : C23);
  }
  int ari = a % 3;
  double ar = (ari == 0) ? 0.667 : ((ari == 1) ? 1.0 : 1.5);
  int gy = pos / oh, gx = pos % oh;
  float cy = 0.5f * (float)stride + (float)(stride * gy);
  float cx = 0.5f * (float)stride + (float)(stride * gx);
  double ss = sqrt(ar);
  double hd = (size * sc) / ss;
  double wd = (size * sc) * ss;
  float hh = (float)(hd * 0.5), wh = (float)(wd * 0.5);
  int y0 = (int)((cy - hh) + 224.0f), x0 = (int)((cx - wh) + 224.0f);
  int y1i = (int)((cy + hh) + 224.0f), x1i = (int)((cx + wh) + 224.0f);
  anch[i * 4 + 0] = y0; anch[i * 4 + 1] = x0;
  anch[i * 4 + 2] = y1i; anch[i * 4 + 3] = x1i;
  areas[i] = (float)(y1i - y0) * (float)(x1i - x0);
}

__global__ __launch_bounds__(256) void prep_small(int* __restrict__ anch,
                                                  float* __restrict__ areas,
                                                  const float* __restrict__ w2,
                                                  float* __restrict__ w2p,
                                                  const float* __restrict__ w3,
                                                  float* __restrict__ w3p) {
  int b = blockIdx.x, t = threadIdx.x;
  if (b < 7) { anchors_body(b * 256 + t, anch, areas); return; }
  const float* src; float* dst; int idx;
  if (b < 7 + 576) { src = w2; dst = w2p; idx = (b - 7) * 256 + t; }
  else             { src = w3; dst = w3p; idx = (b - 583) * 256 + t; }
  if (idx >= 128 * 9 * 128) return;
  int c = idx % 128; int r2 = idx / 128; int tap = r2 % 9; int o = r2 / 9;
  dst[idx] = src[(o * 128 + c) * 9 + tap];
}

// ---------------- f32 -> f16 hi/lo split (linear, scale WSCALE) -------------
__global__ __launch_bounds__(256) void split_w(const float* __restrict__ src,
                                               _Float16* __restrict__ h,
                                               _Float16* __restrict__ l, int n8) {
  int i = blockIdx.x * 256 + threadIdx.x;
  if (i >= n8) return;
  float4 v0 = *(const float4*)(src + (size_t)i * 8);
  float4 v1 = *(const float4*)(src + (size_t)i * 8 + 4);
  float vv[8] = {v0.x, v0.y, v0.z, v0.w, v1.x, v1.y, v1.z, v1.w};
  h8 vh, vl;
#pragma unroll
  for (int j = 0; j < 8; ++j) {
    float s = vv[j] * WSCALE;
    _Float16 a = (_Float16)s;
    vh[j] = a; vl[j] = (_Float16)(s - (float)a);
  }
  *(h8*)(h + (size_t)i * 8) = vh;
  *(h8*)(l + (size_t)i * 8) = vl;
}

// ---------------- fused w1 permute + split: h/l[o][tap][c] from w1[o][c][tap]
__global__ __launch_bounds__(256) void split_w1(const float* __restrict__ w1,
                                                _Float16* __restrict__ h,
                                                _Float16* __restrict__ l) {
  int idx = blockIdx.x * 256 + threadIdx.x;
  if (idx >= 128 * 9 * 2048) return;
  int c = idx & 2047; int rest = idx >> 11; int tap = rest % 9; int o = rest / 9;
  float v = w1[(o * 2048 + c) * 9 + tap] * WSCALE;
  _Float16 a = (_Float16)v;
  h[idx] = a; l[idx] = (_Float16)(v - (float)a);
}

// ---------------- x patchify -> A hi/lo [1664][3072] (scale ASCALE) ---------
__global__ __launch_bounds__(256) void split_x(const float* __restrict__ x,
                                               _Float16* __restrict__ Ah,
                                               _Float16* __restrict__ Al) {
  int i = blockIdx.x * 256 + threadIdx.x;
  if (i >= 1664 * 384) return;
  int kq = i % 384, m = i / 384;
  int k = kq * 8;
  h8 vh = {}, vl = {};
  if (m < 1568) {
    int b = m / 196, pos = m % 196;
    int c = k >> 10, r = (k >> 5) & 31, col = k & 31;
    int py = (pos / 14) * 32 + r, px = (pos % 14) * 32 + col;
    const float* sp2 = x + (((size_t)(b * 3 + c) * 448 + py) * 448 + px);
    float4 v0 = *(const float4*)sp2;
    float4 v1 = *(const float4*)(sp2 + 4);
    float vv[8] = {v0.x, v0.y, v0.z, v0.w, v1.x, v1.y, v1.z, v1.w};
#pragma unroll
    for (int j = 0; j < 8; ++j) {
      float s = vv[j] * ASCALE;
      _Float16 a = (_Float16)s;
      vh[j] = a; vl[j] = (_Float16)(s - (float)a);
    }
  }
  *(h8*)(Ah + (size_t)m * 3072 + k) = vh;
  *(h8*)(Al + (size_t)m * 3072 + k) = vl;
}

// ---------------- backbone GEMM: A reg-pipelined (2-deep), B LDS-dbuf -------
// Writes raw f32 dot-product partials P[z][1664][2048]; split-K=3.
__global__ __launch_bounds__(256, 3) void gemm_bb_mfma(
    const _Float16* __restrict__ Ah, const _Float16* __restrict__ Al,
    const _Float16* __restrict__ Bh, const _Float16* __restrict__ Bl,
    float* __restrict__ P) {
  __shared__ __align__(16) char lds[32768];  // 2 bufs x (Bh 8KB | Bl 8KB)
  const int t = threadIdx.x;
  // XCD-chunked bijective swizzle: 208 xy-blocks = 8 XCD x 26.
  const int bid = blockIdx.x + 13 * blockIdx.y;
  const int orig = (bid & 7) * 26 + (bid >> 3);
  const int m0 = (orig % 13) * 128, n0 = (orig / 13) * 128;
  const int kz = blockIdx.z;  // 0..2
  const int lane = t & 63, w = t >> 6;
  const int wm = (w >> 1) * 64, wn = (w & 1) * 64;
  const int lrow = lane & 15, kg = lane >> 4, kg8 = kg * 8;

  int offB[4];
#pragma unroll
  for (int i = 0; i < 4; ++i) {
    int bb2 = (wn + i * 16 + lrow) * 64 + kg * 16;
    offB[i] = bb2 ^ (((bb2 >> 7) & 3) << 4);
  }
  size_t aro[4];
#pragma unroll
  for (int i = 0; i < 4; ++i)
    aro[i] = (size_t)(m0 + wm + i * 16 + lrow) * 3072 + kg8;

  size_t gBo[2];
  int ldso[2];
#pragma unroll
  for (int e = 0; e < 2; ++e) {
    int p = e * 256 + t;
    int lsl = p ^ ((p >> 3) & 3);   // inverse swizzle (involution) in slot units
    int row = lsl >> 2, kq = lsl & 3;
    gBo[e] = (size_t)(n0 + row) * 3072 + kq * 8;
    ldso[e] = e * 4096 + (t & 192) * 16;
  }

  auto LOADA = [&](int k0, h8 (&ha)[4], h8 (&la)[4]) {
#pragma unroll
    for (int i = 0; i < 4; ++i) {
      ha[i] = *(const h8*)(Ah + aro[i] + k0);
      la[i] = *(const h8*)(Al + aro[i] + k0);
    }
  };
  auto STAGE = [&](int buf, int k0) {
    char* L = lds + buf * 16384;
#pragma unroll
    for (int e = 0; e < 2; ++e) {
      gload16(Bh + gBo[e] + k0, L + ldso[e]);
      gload16(Bl + gBo[e] + k0, L + 8192 + ldso[e]);
    }
  };

  f32x4 acc[4][4] = {};
  auto COMPUTE = [&](const char* L, h8 (&ha)[4], h8 (&la)[4]) {
    h8 fbh[4], fbl[4];
#pragma unroll
    for (int j = 0; j < 4; ++j) {
      fbh[j] = *(const h8*)(L + offB[j]);
      fbl[j] = *(const h8*)(L + 8192 + offB[j]);
    }
#pragma unroll
    for (int i = 0; i < 4; ++i)
#pragma unroll
      for (int j = 0; j < 4; ++j)
        acc[i][j] = __builtin_amdgcn_mfma_f32_16x16x32_f16(ha[i], fbh[j], acc[i][j], 0, 0, 0);
#pragma unroll
    for (int i = 0; i < 4; ++i)
#pragma unroll
      for (int j = 0; j < 4; ++j)
        acc[i][j] = __builtin_amdgcn_mfma_f32_16x16x32_f16(ha[i], fbl[j], acc[i][j], 0, 0, 0);
#pragma unroll
    for (int i = 0; i < 4; ++i)
#pragma unroll
      for (int j = 0; j < 4; ++j)
        acc[i][j] = __builtin_amdgcn_mfma_f32_16x16x32_f16(la[i], fbh[j], acc[i][j], 0, 0, 0);
  };

  const int kbeg = kz * 1024, kend = kbeg + 1024;  // 16 phase-pairs exact
  h8 a0h[4], a0l[4], a1h[4], a1l[4];
  LOADA(kbeg, a0h, a0l);
  STAGE(0, kbeg);
  __syncthreads();
  for (int k0 = kbeg; k0 < kend; k0 += 64) {
    // phase 0: prefetch k0+32 (regs A1 + LDS buf1), compute k0 (A0, buf0)
    if (k0 + 32 < kend) { LOADA(k0 + 32, a1h, a1l); STAGE(1, k0 + 32); }
    COMPUTE(lds, a0h, a0l);
    __syncthreads();
    // phase 1: prefetch k0+64 (A0, buf0), compute k0+32 (A1, buf1)
    if (k0 + 64 < kend) { LOADA(k0 + 64, a0h, a0l); STAGE(0, k0 + 64); }
    COMPUTE(lds + 16384, a1h, a1l);
    __syncthreads();
  }
  float* Pz = P + (size_t)kz * PSLAB;
  const int prow = (lane >> 4) * 4;
#pragma unroll
  for (int i = 0; i < 4; ++i) {
#pragma unroll
    for (int j = 0; j < 4; ++j) {
      int n = n0 + wn + j * 16 + lrow;
#pragma unroll
      for (int r = 0; r < 4; ++r) {
        int m = m0 + wm + i * 16 + prow + r;
        Pz[(size_t)m * 2048 + n] = acc[i][j][r];
      }
    }
  }
}

// ---------------- split-K reduce: C = relu((p0+p1+p2)*RSCALE + bias) --------
// WRITE_SPLIT: also emit h/l f16 split (ASCALE) incl. zeroed rows 1568..1663.
template <int WRITE_SPLIT>
__global__ __launch_bounds__(256) void bb_reduce(const float* __restrict__ P,
                                                 const float* __restrict__ bias,
                                                 float* __restrict__ raw,
                                                 _Float16* __restrict__ h,
                                                 _Float16* __restrict__ l) {
  int idx = blockIdx.x * 256 + threadIdx.x;
  int m = idx >> 8, col = (idx & 255) * 8;
  if (WRITE_SPLIT) {
    if (m >= 1664) return;
    if (m >= 1568) {
      h8 z = {};
      *(h8*)(h + (size_t)m * 2048 + col) = z;
      *(h8*)(l + (size_t)m * 2048 + col) = z;
      return;
    }
  } else {
    if (m >= 1568) return;
  }
  size_t o = (size_t)m * 2048 + col;
  float v[8];
#pragma unroll
  for (int q = 0; q < 2; ++q) {
    float4 s0 = *(const float4*)(P + o + q * 4);
    float4 s1 = *(const float4*)(P + PSLAB + o + q * 4);
    float4 s2 = *(const float4*)(P + 2 * PSLAB + o + q * 4);
    float4 b = *(const float4*)(bias + col + q * 4);
    v[q * 4 + 0] = fmaxf(fmaf(s0.x + s1.x + s2.x, RSCALE, b.x), 0.f);
    v[q * 4 + 1] = fmaxf(fmaf(s0.y + s1.y + s2.y, RSCALE, b.y), 0.f);
    v[q * 4 + 2] = fmaxf(fmaf(s0.z + s1.z + s2.z, RSCALE, b.z), 0.f);
    v[q * 4 + 3] = fmaxf(fmaf(s0.w + s1.w + s2.w, RSCALE, b.w), 0.f);
  }
  *(float4*)(raw + o) = make_float4(v[0], v[1], v[2], v[3]);
  *(float4*)(raw + o + 4) = make_float4(v[4], v[5], v[6], v[7]);
  if (WRITE_SPLIT) {
    h8 vh, vl;
#pragma unroll
    for (int j = 0; j < 8; ++j) {
      float s = v[j] * ASCALE;
      _Float16 a = (_Float16)s;
      vh[j] = a; vl[j] = (_Float16)(s - (float)a);
    }
    *(h8*)(h + o) = vh;
    *(h8*)(l + o) = vl;
  }
}

// ---------------- navigator y1 GEMM: A reg-pipelined (im2col), B LDS-dbuf ---
__global__ __launch_bounds__(256, 3) void gemm_nav_mfma(
    const _Float16* __restrict__ Ah, const _Float16* __restrict__ Al,
    const _Float16* __restrict__ Bh, const _Float16* __restrict__ Bl,
    float* __restrict__ part) {
  __shared__ __align__(16) char lds[32768];
  const int t = threadIdx.x;
  // XCD-chunked bijective swizzle: 416 blocks = 8 XCD x 52.
  const int bid = blockIdx.x + 13 * blockIdx.y;
  const int orig = (bid & 7) * 52 + (bid >> 3);
  const int m0 = (orig % 13) * 128;
  const int sp = orig / 13;  // 0..31
  const int lane = t & 63, w = t >> 6;
  const int wm = (w >> 1) * 64, wn = (w & 1) * 64;
  const int lrow = lane & 15, kg = lane >> 4, kg8 = kg * 8;

  int offB[4];
#pragma unroll
  for (int i = 0; i < 4; ++i) {
    int bb2 = (wn + i * 16 + lrow) * 64 + kg * 16;
    offB[i] = bb2 ^ (((bb2 >> 7) & 3) << 4);
  }
  // Per-fragment im2col row state (4 rows per thread).
  int fb[4], fpy[4], fpx[4], fvalid[4];
#pragma unroll
  for (int i = 0; i < 4; ++i) {
    int m = m0 + wm + i * 16 + lrow;
    fvalid[i] = (m < 1568);
    int b = m / 196, pos = m % 196;
    fb[i] = b; fpy[i] = pos / 14; fpx[i] = pos % 14;
  }

  size_t gBo[2];
  int ldso[2];
#pragma unroll
  for (int e = 0; e < 2; ++e) {
    int p = e * 256 + t;
    int lsl = p ^ ((p >> 3) & 3);
    int row = lsl >> 2, kq = lsl & 3;
    gBo[e] = (size_t)row * 18432 + kq * 8;
    ldso[e] = e * 4096 + (t & 192) * 16;
  }

  auto LOADA = [&](int k0, h8 (&ha)[4], h8 (&la)[4]) {
    const int tap = k0 >> 11;   // 32 | 2048: no tap straddle within a K-step
    const int c = k0 & 2047;
    const int dy = tap / 3 - 1, dx = tap % 3 - 1;
#pragma unroll
    for (int i = 0; i < 4; ++i) {
      int sy = fpy[i] + dy, sx = fpx[i] + dx;
      bool ok = fvalid[i] && ((unsigned)sy < 14u) && ((unsigned)sx < 14u);
      size_t rowi = ok ? (size_t)(fb[i] * 196 + sy * 14 + sx) : (size_t)1600;
      size_t ao = rowi * 2048 + c + kg8;
      ha[i] = *(const h8*)(Ah + ao);
      la[i] = *(const h8*)(Al + ao);
    }
  };
  auto STAGE = [&](int buf, int k0) {
    char* L = lds + buf * 16384;
#pragma unroll
    for (int e = 0; e < 2; ++e) {
      gload16(Bh + gBo[e] + k0, L + ldso[e]);
      gload16(Bl + gBo[e] + k0, L + 8192 + ldso[e]);
    }
  };

  f32x4 acc[4][4] = {};
  auto COMPUTE = [&](const char* L, h8 (&ha)[4], h8 (&la)[4]) {
    h8 fbh[4], fbl[4];
#pragma unroll
    for (int j = 0; j < 4; ++j) {
      fbh[j] = *(const h8*)(L + offB[j]);
      fbl[j] = *(const h8*)(L + 8192 + offB[j]);
    }
#pragma unroll
    for (int i = 0; i < 4; ++i)
#pragma unroll
      for (int j = 0; j < 4; ++j)
        acc[i][j] = __builtin_amdgcn_mfma_f32_16x16x32_f16(ha[i], fbh[j], acc[i][j], 0, 0, 0);
#pragma unroll
    for (int i = 0; i < 4; ++i)
#pragma unroll
      for (int j = 0; j < 4; ++j)
        acc[i][j] = __builtin_amdgcn_mfma_f32_16x16x32_f16(ha[i], fbl[j], acc[i][j], 0, 0, 0);
#pragma unroll
    for (int i = 0; i < 4; ++i)
#pragma unroll
      for (int j = 0; j < 4; ++j)
        acc[i][j] = __builtin_amdgcn_mfma_f32_16x16x32_f16(la[i], fbh[j], acc[i][j], 0, 0, 0);
  };

  const int kbeg = sp * 576, kend = kbeg + 576;  // 9 phase-pairs exact
  h8 a0h[4], a0l[4], a1h[4], a1l[4];
  LOADA(kbeg, a0h, a0l);
  STAGE(0, kbeg);
  __syncthreads();
  for (int k0 = kbeg; k0 < kend; k0 += 64) {
    if (k0 + 32 < kend) { LOADA(k0 + 32, a1h, a1l); STAGE(1, k0 + 32); }
    COMPUTE(lds, a0h, a0l);
    __syncthreads();
    if (k0 + 64 < kend) { LOADA(k0 + 64, a0h, a0l); STAGE(0, k0 + 64); }
    COMPUTE(lds + 16384, a1h, a1l);
    __syncthreads();
  }
  const int prow = (lane >> 4) * 4;
#pragma unroll
  for (int i = 0; i < 4; ++i) {
#pragma unroll
    for (int j = 0; j < 4; ++j) {
      int n = wn + j * 16 + lrow;
#pragma unroll
      for (int r = 0; r < 4; ++r) {
        int m = m0 + wm + i * 16 + prow + r;
        if (m < 1568)
          part[((size_t)sp * 1568 + m) * 128 + n] = acc[i][j][r] * RSCALE;
      }
    }
  }
}

__global__ __launch_bounds__(256) void y1_reduce(const float* __restrict__ part,
                                                 const float* __restrict__ b1,
                                                 float* __restrict__ y1) {
  int idx = blockIdx.x * 256 + threadIdx.x;
  if (idx >= 1568 * 128) return;
  int o = idx & 127;
  float s = b1[o];
#pragma unroll
  for (int sp = 0; sp < 32; ++sp) s += part[(size_t)sp * 1568 * 128 + idx];
  y1[idx] = fmaxf(s, 0.f);
}

// ---------------- small 3x3 stride-2 pad-1 convs (128->128 ch, NHWC) --------
__global__ __launch_bounds__(256) void conv3x3s2(const float* __restrict__ in,
                                                 const float* __restrict__ wp,
                                                 const float* __restrict__ bias,
                                                 float* __restrict__ out,
                                                 int Hin, int Hout) {
  int idx = blockIdx.x * 256 + threadIdx.x;
  int total = 8 * Hout * Hout * 128;
  if (idx >= total) return;
  int o = idx & 127; int pos = idx >> 7;
  int ox = pos % Hout; int t2 = pos / Hout; int oy = t2 % Hout; int b = t2 / Hout;
  float acc = bias[o];
  for (int dy = 0; dy < 3; ++dy) {
    int iy = 2 * oy - 1 + dy;
    if (iy < 0 || iy >= Hin) continue;
    for (int dx = 0; dx < 3; ++dx) {
      int ix = 2 * ox - 1 + dx;
      if (ix < 0 || ix >= Hin) continue;
      const float* ip = in + ((b * Hin + iy) * Hin + ix) * 128;
      const float* wgt = wp + (o * 9 + dy * 3 + dx) * 128;
#pragma unroll 4
      for (int c = 0; c < 128; c += 4) {
        float4 a = *(const float4*)(ip + c);
        float4 ww = *(const float4*)(wgt + c);
        acc += a.x * ww.x + a.y * ww.y + a.z * ww.z + a.w * ww.w;
      }
    }
  }
  out[idx] = fmaxf(acc, 0.f);
}

// ---------------- rpn scores ------------------------------------------------
__global__ __launch_bounds__(256) void scores_kernel(
    const float* __restrict__ y1, const float* __restrict__ y2,
    const float* __restrict__ y3, const float* __restrict__ t1w,
    const float* __restrict__ t1b, const float* __restrict__ t2w,
    const float* __restrict__ t2b, const float* __restrict__ t3w,
    const float* __restrict__ t3b, float* __restrict__ scores) {
  int idx = blockIdx.x * 256 + threadIdx.x;
  if (idx >= 8 * 1614) return;
  int b = idx / 1614, sI = idx % 1614;
  const float* f; const float* w; float bias;
  if (sI < 1176) {
    int a = sI / 196;
    f = y1 + (b * 196 + (sI % 196)) * 128; w = t1w + a * 128; bias = t1b[a];
  } else if (sI < 1470) {
    int r = sI - 1176; int a = r / 49;
    f = y2 + (b * 49 + (r % 49)) * 128; w = t2w + a * 128; bias = t2b[a];
  } else {
    int r = sI - 1470; int a = r / 16;
    f = y3 + (b * 16 + (r % 16)) * 128; w = t3w + a * 128; bias = t3b[a];
  }
  float acc = 0.f;
  for (int c = 0; c < 128; c += 4) {
    float4 a4 = *(const float4*)(f + c);
    float4 w4 = *(const float4*)(w + c);
    acc += a4.x * w4.x + a4.y * w4.y + a4.z * w4.z + a4.w * w4.w;
  }
  scores[idx] = acc + bias;
}

// ---------------- greedy NMS (per batch block) ------------------------------
__global__ __launch_bounds__(256) void nms_kernel(const float* __restrict__ scores,
                                                  const int* __restrict__ anch,
                                                  const float* __restrict__ areas,
                                                  int* __restrict__ boxes) {
  const int b = blockIdx.x, t = threadIdx.x;
  const float* s = scores + b * 1614;
  __shared__ unsigned char valid[1614];
  __shared__ float rv[256];
  __shared__ int ri[256];
  for (int i = t; i < 1614; i += 256) valid[i] = 1;
  __syncthreads();
  for (int n = 0; n < 4; ++n) {
    float best = -INFINITY; int bi = 0x7fffffff;
    for (int i = t; i < 1614; i += 256) {
      if (valid[i]) {
        float v = s[i];
        if (v > best || (v == best && i < bi)) { best = v; bi = i; }
      }
    }
    rv[t] = best; ri[t] = bi;
    __syncthreads();
    for (int off = 128; off > 0; off >>= 1) {
      if (t < off) {
        float ov = rv[t + off]; int oi = ri[t + off];
        if (ov > rv[t] || (ov == rv[t] && oi < ri[t])) { rv[t] = ov; ri[t] = oi; }
      }
      __syncthreads();
    }
    int sel = ri[0];
    if (sel > 1613) sel = 0;
    const int4 bb = ((const int4*)anch)[sel];
    const float Ai = areas[sel];
    if (t == 0) ((int4*)boxes)[b * 4 + n] = bb;
    __syncthreads();
    for (int i = t; i < 1614; i += 256) {
      if (!valid[i]) continue;
      const int4 ab = ((const int4*)anch)[i];
      float sy = fmaxf((float)ab.x, (float)bb.x);
      float sx = fmaxf((float)ab.y, (float)bb.y);
      float ey = fminf((float)ab.z, (float)bb.z);
      float ex = fminf((float)ab.w, (float)bb.w);
      float ly = ey - sy, lx = ex - sx;
      float inter = (ly < 0.f || lx < 0.f) ? 0.f : ly * lx;
      float iou = inter / (areas[i] + Ai - inter);
      if (iou >= 0.25f) valid[i] = 0;
    }
    __syncthreads();
  }
}

// ---------------- bilinear crop -> A hi/lo (im2col layout, scaled) ----------
__global__ __launch_bounds__(256) void crop_kernel(const float* __restrict__ x,
                                                   const int* __restrict__ boxes,
                                                   _Float16* __restrict__ Ah,
                                                   _Float16* __restrict__ Al) {
  int idx = blockIdx.x * 256 + threadIdx.x;
  if (idx >= 32 * 3 * 224 * 224) return;
  int px = idx % 224; int t1 = idx / 224; int py = t1 % 224; int t2 = t1 / 224;
  int c = t2 % 3; int p = t2 / 3;
  int b = p >> 2;
  const int4 bb = ((const int4*)boxes)[p];
  float ty = (float)py / 223.0f;
  float txf = (float)px / 223.0f;
  float ys = (float)bb.x + ty * (float)(bb.z - bb.x - 1);
  float xs = (float)bb.y + txf * (float)(bb.w - bb.y - 1);
  float yf = floorf(ys), xf = floorf(xs);
  float wy = ys - yf, wx = xs - xf;
  int yl = (int)yf, xl = (int)xf;
  int yh = min(yl + 1, 895), xh = min(xl + 1, 895);
  const float* img = x + (size_t)(b * 3 + c) * 448 * 448;
  auto samp = [&](int yy, int xx) -> float {
    yy -= 224; xx -= 224;
    if (yy < 0 || yy >= 448 || xx < 0 || xx >= 448) return 0.f;
    return img[yy * 448 + xx];
  };
  float v00 = samp(yl, xl), v01 = samp(yl, xh);
  float v10 = samp(yh, xl), v11 = samp(yh, xh);
  float top = v00 * (1.f - wx) + v01 * wx;
  float bot = v10 * (1.f - wx) + v11 * wx;
  float val = top * (1.f - wy) + bot * wy;
  int i = py >> 5, r = py & 31, j = px >> 5, col = px & 31;
  int m = p * 49 + i * 7 + j;
  int k = (c << 10) + (r << 5) + col;
  float s = val * ASCALE;
  _Float16 a = (_Float16)s;
  Ah[(size_t)m * 3072 + k] = a;
  Al[(size_t)m * 3072 + k] = (_Float16)(s - (float)a);
}

// ---------------- row-parallel spatial mean ----------------------------------
// grid = groups * 32; block = 64 cols x 4 row-lanes.
__global__ __launch_bounds__(256) void mean_kernel(const float* __restrict__ in,
                                                   float* __restrict__ out,
                                                   int rows) {
  int g = blockIdx.x >> 5, chunk = blockIdx.x & 31;
  int col = chunk * 64 + (threadIdx.x & 63), rl = threadIdx.x >> 6;
  const float* base = in + ((size_t)g * rows) * 2048 + col;
  float s = 0.f;
  for (int r = rl; r < rows; r += 4) s += base[(size_t)r * 2048];
  __shared__ float red[4][64];
  red[rl][threadIdx.x & 63] = s;
  __syncthreads();
  if (rl == 0) {
    int c = threadIdx.x & 63;
    out[(size_t)g * 2048 + col] =
        ((red[0][c] + red[1][c]) + (red[2][c] + red[3][c])) / (float)rows;
  }
}

// ---------------- final linear: one wave per (b, class) ---------------------
__global__ __launch_bounds__(256) void final_kernel(const float* __restrict__ pfeat,
                                                    const float* __restrict__ rfeat,
                                                    const float* __restrict__ cw,
                                                    const float* __restrict__ cb,
                                                    float* __restrict__ out) {
  int gw = (blockIdx.x * 256 + threadIdx.x) >> 6;
  int lane = threadIdx.x & 63;
  if (gw >= 1600) return;
  int b = gw / 200, j = gw % 200;
  const float* wr = cw + (size_t)j * 10240;
  const float* pf = pfeat + (size_t)b * 8192;
  float acc = 0.f;
  for (int k = lane * 4; k < 8192; k += 256) {
    float4 a = *(const float4*)(pf + k);
    float4 w = *(const float4*)(wr + k);
    acc += a.x * w.x + a.y * w.y + a.z * w.z + a.w * w.w;
  }
  const float* rf = rfeat + (size_t)b * 2048;
  const float* wr2 = wr + 8192;
  for (int k = lane * 4; k < 2048; k += 256) {
    float4 a = *(const float4*)(rf + k);
    float4 w = *(const float4*)(wr2 + k);
    acc += a.x * w.x + a.y * w.y + a.z * w.z + a.w * w.w;
  }
#pragma unroll
  for (int off = 32; off > 0; off >>= 1) acc += __shfl_down(acc, off, 64);
  if (lane == 0) out[b * 200 + j] = acc + cb[j];
}

// ---------------------------------------------------------------------------
extern "C" void kernel_launch(void* const* d_in, const int* in_sizes, int n_in,
                              void* d_out, int out_size, void* d_ws, size_t ws_size,
                              hipStream_t stream) {
  const float* x   = (const float*)d_in[0];
  const float* bbw = (const float*)d_in[1];
  const float* bbb = (const float*)d_in[2];
  const float* w1  = (const float*)d_in[3];
  const float* b1  = (const float*)d_in[4];
  const float* t1w = (const float*)d_in[5];
  const float* t1b = (const float*)d_in[6];
  const float* w2  = (const float*)d_in[7];
  const float* b2  = (const float*)d_in[8];
  const float* t2w = (const float*)d_in[9];
  const float* t2b = (const float*)d_in[10];
  const float* w3  = (const float*)d_in[11];
  const float* b3  = (const float*)d_in[12];
  const float* t3w = (const float*)d_in[13];
  const float* t3b = (const float*)d_in[14];
  const float* cw  = (const float*)d_in[15];
  const float* cb  = (const float*)d_in[16];
  float* out = (float*)d_out;

  char* p = (char*)d_ws;
  auto alloc = [&](size_t bytes) -> char* {
    char* r = p; p += (bytes + 255) & ~(size_t)255; return r;
  };
  int*      anch  = (int*)     alloc((size_t)1614 * 4 * 4);
  float*    areas = (float*)   alloc((size_t)1614 * 4);
  _Float16* bWh   = (_Float16*)alloc((size_t)2048 * 3072 * 2);
  _Float16* bWl   = (_Float16*)alloc((size_t)2048 * 3072 * 2);
  _Float16* w1h   = (_Float16*)alloc((size_t)128 * 18432 * 2);
  _Float16* w1l   = (_Float16*)alloc((size_t)128 * 18432 * 2);
  _Float16* Ahh   = (_Float16*)alloc((size_t)1664 * 3072 * 2);
  _Float16* All   = (_Float16*)alloc((size_t)1664 * 3072 * 2);
  _Float16* rawh  = (_Float16*)alloc((size_t)1664 * 2048 * 2);
  _Float16* rawl  = (_Float16*)alloc((size_t)1664 * 2048 * 2);
  float*    raw   = (float*)   alloc((size_t)1568 * 2048 * 4);
  float*    w2p   = (float*)   alloc((size_t)128 * 9 * 128 * 4);
  float*    w3p   = (float*)   alloc((size_t)128 * 9 * 128 * 4);
  // P (split-K=3 partials) aliases y1s (32x1568x128 f32): disjoint lifetimes.
  char*     big   = alloc((size_t)4 * PSLAB * 4);
  float*    Pbuf  = (float*)big;
  float*    y1s   = (float*)big;
  float*    y1v   = (float*)   alloc((size_t)1568 * 128 * 4);
  float*    y2v   = (float*)   alloc((size_t)392 * 128 * 4);
  float*    y3v   = (float*)   alloc((size_t)128 * 128 * 4);
  float*    sc    = (float*)   alloc((size_t)8 * 1614 * 4);
  int*      boxes = (int*)     alloc((size_t)8 * 4 * 4 * 4);
  float*    pfeat = (float*)   alloc((size_t)32 * 2048 * 4);
  float*    rfeat = (float*)   alloc((size_t)8 * 2048 * 4);

  prep_small<<<7 + 576 + 576, 256, 0, stream>>>(anch, areas, w2, w2p, w3, w3p);
  split_w<<<(2048 * 3072 / 8 + 255) / 256, 256, 0, stream>>>(bbw, bWh, bWl, 2048 * 3072 / 8);
  split_w1<<<(128 * 9 * 2048 + 255) / 256, 256, 0, stream>>>(w1, w1h, w1l);
  split_x<<<(1664 * 384 + 255) / 256, 256, 0, stream>>>(x, Ahh, All);

  gemm_bb_mfma<<<dim3(13, 16, 3), 256, 0, stream>>>(Ahh, All, bWh, bWl, Pbuf);
  bb_reduce<1><<<1664, 256, 0, stream>>>(Pbuf, bbb, raw, rawh, rawl);
  gemm_nav_mfma<<<dim3(13, 32), 256, 0, stream>>>(rawh, rawl, w1h, w1l, y1s);
  y1_reduce<<<(1568 * 128 + 255) / 256, 256, 0, stream>>>(y1s, b1, y1v);
  mean_kernel<<<8 * 32, 256, 0, stream>>>(raw, rfeat, 196);
  conv3x3s2<<<(8 * 7 * 7 * 128 + 255) / 256, 256, 0, stream>>>(y1v, w2p, b2, y2v, 14, 7);
  conv3x3s2<<<(8 * 4 * 4 * 128 + 255) / 256, 256, 0, stream>>>(y2v, w3p, b3, y3v, 7, 4);
  scores_kernel<<<(8 * 1614 + 255) / 256, 256, 0, stream>>>(
      y1v, y2v, y3v, t1w, t1b, t2w, t2b, t3w, t3b, sc);
  nms_kernel<<<8, 256, 0, stream>>>(sc, anch, areas, boxes);
  crop_kernel<<<(32 * 3 * 224 * 224) / 256, 256, 0, stream>>>(x, boxes, Ahh, All);
  gemm_bb_mfma<<<dim3(13, 16, 3), 256, 0, stream>>>(Ahh, All, bWh, bWl, Pbuf);
  bb_reduce<0><<<1568, 256, 0, stream>>>(Pbuf, bbb, raw, rawh, rawl);
  mean_kernel<<<32 * 32, 256, 0, stream>>>(raw, pfeat, 49);
  final_kernel<<<400, 256, 0, stream>>>(pfeat, rfeat, cw, cb, out);
}

// Round 9
// 519.637 us; speedup vs baseline: 1.7389x; 1.7389x over previous
//
#include <hip/hip_runtime.h>
#include <math.h>

// ---------------------------------------------------------------------------
// NTSNet forward. Big GEMMs on MFMA via 2-way f16 split (3 products: hh,hl,lh)
// R2: parallel means. R3: split-K. R4: 2-phase dbuf + XCD swizzle. R5: fused
// prep. R6: A direct (REGRESSED: same-iter loads). R7: A reg-pipelined 2-deep
// (REGRESSED: launch_bounds(256,3) capped VGPR at 168 -> spills, 606MB scratch
// writes/dispatch). R8: same structure, launch_bounds(256,2) -> 256 VGPR
// budget, no spill, 2 blocks/CU overlap (the R5-proven residency).
// ---------------------------------------------------------------------------

typedef _Float16 h8 __attribute__((ext_vector_type(8)));
typedef float f32x4 __attribute__((ext_vector_type(4)));

#define ASCALE 256.0f
#define WSCALE 16384.0f
#define RSCALE (1.0f / (256.0f * 16384.0f))
#define PSLAB ((size_t)1664 * 2048)

__device__ __forceinline__ void gload16(const void* g, void* l) {
  __builtin_amdgcn_global_load_lds(
      (__attribute__((address_space(1))) void*)(void*)(uintptr_t)g,
      (__attribute__((address_space(3))) void*)l, 16, 0, 0);
}

// ---------------- merged small prep: anchors + w2/w3 permutes ---------------
__device__ void anchors_body(int i, int* anch, float* areas) {
  if (i >= 1614) return;
  int stride, oh, a, pos;
  double size, sc;
  const double C13 = 1.2599210498948732;
  const double C23 = 1.5874010519681994;
  if (i < 1176) {
    stride = 32; size = 48.0; oh = 14; a = i / 196; pos = i % 196;
    sc = (a / 3 == 0) ? C13 : C23;
  } else if (i < 1470) {
    int r = i - 1176; stride = 64; size = 96.0; oh = 7; a = r / 49; pos = r % 49;
    sc = (a / 3 == 0) ? C13 : C23;
  } else {
    int r = i - 1470; stride = 128; size = 192.0; oh = 4; a = r / 16; pos = r % 16;
    int si = a / 3;
    sc = (si == 0) ? 1.0 : ((si == 1) ? C13 : C23);
  }
  int ari = a % 3;
  double ar = (ari == 0) ? 0.667 : ((ari == 1) ? 1.0 : 1.5);
  int gy = pos / oh, gx = pos % oh;
  float cy = 0.5f * (float)stride + (float)(stride * gy);
  float cx = 0.5f * (float)stride + (float)(stride * gx);
  double ss = sqrt(ar);
  double hd = (size * sc) / ss;
  double wd = (size * sc) * ss;
  float hh = (float)(hd * 0.5), wh = (float)(wd * 0.5);
  int y0 = (int)((cy - hh) + 224.0f), x0 = (int)((cx - wh) + 224.0f);
  int y1i = (int)((cy + hh) + 224.0f), x1i = (int)((cx + wh) + 224.0f);
  anch[i * 4 + 0] = y0; anch[i * 4 + 1] = x0;
  anch[i * 4 + 2] = y1i; anch[i * 4 + 3] = x1i;
  areas[i] = (float)(y1i - y0) * (float)(x1i - x0);
}

__global__ __launch_bounds__(256) void prep_small(int* __restrict__ anch,
                                                  float* __restrict__ areas,
                                                  const float* __restrict__ w2,
                                                  float* __restrict__ w2p,
                                                  const float* __restrict__ w3,
                                                  float* __restrict__ w3p) {
  int b = blockIdx.x, t = threadIdx.x;
  if (b < 7) { anchors_body(b * 256 + t, anch, areas); return; }
  const float* src; float* dst; int idx;
  if (b < 7 + 576) { src = w2; dst = w2p; idx = (b - 7) * 256 + t; }
  else             { src = w3; dst = w3p; idx = (b - 583) * 256 + t; }
  if (idx >= 128 * 9 * 128) return;
  int c = idx % 128; int r2 = idx / 128; int tap = r2 % 9; int o = r2 / 9;
  dst[idx] = src[(o * 128 + c) * 9 + tap];
}

// ---------------- f32 -> f16 hi/lo split (linear, scale WSCALE) -------------
__global__ __launch_bounds__(256) void split_w(const float* __restrict__ src,
                                               _Float16* __restrict__ h,
                                               _Float16* __restrict__ l, int n8) {
  int i = blockIdx.x * 256 + threadIdx.x;
  if (i >= n8) return;
  float4 v0 = *(const float4*)(src + (size_t)i * 8);
  float4 v1 = *(const float4*)(src + (size_t)i * 8 + 4);
  float vv[8] = {v0.x, v0.y, v0.z, v0.w, v1.x, v1.y, v1.z, v1.w};
  h8 vh, vl;
#pragma unroll
  for (int j = 0; j < 8; ++j) {
    float s = vv[j] * WSCALE;
    _Float16 a = (_Float16)s;
    vh[j] = a; vl[j] = (_Float16)(s - (float)a);
  }
  *(h8*)(h + (size_t)i * 8) = vh;
  *(h8*)(l + (size_t)i * 8) = vl;
}

// ---------------- fused w1 permute + split: h/l[o][tap][c] from w1[o][c][tap]
__global__ __launch_bounds__(256) void split_w1(const float* __restrict__ w1,
                                                _Float16* __restrict__ h,
                                                _Float16* __restrict__ l) {
  int idx = blockIdx.x * 256 + threadIdx.x;
  if (idx >= 128 * 9 * 2048) return;
  int c = idx & 2047; int rest = idx >> 11; int tap = rest % 9; int o = rest / 9;
  float v = w1[(o * 2048 + c) * 9 + tap] * WSCALE;
  _Float16 a = (_Float16)v;
  h[idx] = a; l[idx] = (_Float16)(v - (float)a);
}

// ---------------- x patchify -> A hi/lo [1664][3072] (scale ASCALE) ---------
__global__ __launch_bounds__(256) void split_x(const float* __restrict__ x,
                                               _Float16* __restrict__ Ah,
                                               _Float16* __restrict__ Al) {
  int i = blockIdx.x * 256 + threadIdx.x;
  if (i >= 1664 * 384) return;
  int kq = i % 384, m = i / 384;
  int k = kq * 8;
  h8 vh = {}, vl = {};
  if (m < 1568) {
    int b = m / 196, pos = m % 196;
    int c = k >> 10, r = (k >> 5) & 31, col = k & 31;
    int py = (pos / 14) * 32 + r, px = (pos % 14) * 32 + col;
    const float* sp2 = x + (((size_t)(b * 3 + c) * 448 + py) * 448 + px);
    float4 v0 = *(const float4*)sp2;
    float4 v1 = *(const float4*)(sp2 + 4);
    float vv[8] = {v0.x, v0.y, v0.z, v0.w, v1.x, v1.y, v1.z, v1.w};
#pragma unroll
    for (int j = 0; j < 8; ++j) {
      float s = vv[j] * ASCALE;
      _Float16 a = (_Float16)s;
      vh[j] = a; vl[j] = (_Float16)(s - (float)a);
    }
  }
  *(h8*)(Ah + (size_t)m * 3072 + k) = vh;
  *(h8*)(Al + (size_t)m * 3072 + k) = vl;
}

// ---------------- backbone GEMM: A reg-pipelined (2-deep), B LDS-dbuf -------
// Writes raw f32 dot-product partials P[z][1664][2048]; split-K=3.
// launch_bounds(256,2): 256-VGPR budget -- the 2-deep A pipeline needs ~200.
__global__ __launch_bounds__(256, 2) void gemm_bb_mfma(
    const _Float16* __restrict__ Ah, const _Float16* __restrict__ Al,
    const _Float16* __restrict__ Bh, const _Float16* __restrict__ Bl,
    float* __restrict__ P) {
  __shared__ __align__(16) char lds[32768];  // 2 bufs x (Bh 8KB | Bl 8KB)
  const int t = threadIdx.x;
  // XCD-chunked bijective swizzle: 208 xy-blocks = 8 XCD x 26.
  const int bid = blockIdx.x + 13 * blockIdx.y;
  const int orig = (bid & 7) * 26 + (bid >> 3);
  const int m0 = (orig % 13) * 128, n0 = (orig / 13) * 128;
  const int kz = blockIdx.z;  // 0..2
  const int lane = t & 63, w = t >> 6;
  const int wm = (w >> 1) * 64, wn = (w & 1) * 64;
  const int lrow = lane & 15, kg = lane >> 4, kg8 = kg * 8;

  int offB[4];
#pragma unroll
  for (int i = 0; i < 4; ++i) {
    int bb2 = (wn + i * 16 + lrow) * 64 + kg * 16;
    offB[i] = bb2 ^ (((bb2 >> 7) & 3) << 4);
  }
  size_t aro[4];
#pragma unroll
  for (int i = 0; i < 4; ++i)
    aro[i] = (size_t)(m0 + wm + i * 16 + lrow) * 3072 + kg8;

  size_t gBo[2];
  int ldso[2];
#pragma unroll
  for (int e = 0; e < 2; ++e) {
    int p = e * 256 + t;
    int lsl = p ^ ((p >> 3) & 3);   // inverse swizzle (involution) in slot units
    int row = lsl >> 2, kq = lsl & 3;
    gBo[e] = (size_t)(n0 + row) * 3072 + kq * 8;
    ldso[e] = e * 4096 + (t & 192) * 16;
  }

  auto LOADA = [&](int k0, h8 (&ha)[4], h8 (&la)[4]) {
#pragma unroll
    for (int i = 0; i < 4; ++i) {
      ha[i] = *(const h8*)(Ah + aro[i] + k0);
      la[i] = *(const h8*)(Al + aro[i] + k0);
    }
  };
  auto STAGE = [&](int buf, int k0) {
    char* L = lds + buf * 16384;
#pragma unroll
    for (int e = 0; e < 2; ++e) {
      gload16(Bh + gBo[e] + k0, L + ldso[e]);
      gload16(Bl + gBo[e] + k0, L + 8192 + ldso[e]);
    }
  };

  f32x4 acc[4][4] = {};
  auto COMPUTE = [&](const char* L, h8 (&ha)[4], h8 (&la)[4]) {
    h8 fbh[4], fbl[4];
#pragma unroll
    for (int j = 0; j < 4; ++j) {
      fbh[j] = *(const h8*)(L + offB[j]);
      fbl[j] = *(const h8*)(L + 8192 + offB[j]);
    }
#pragma unroll
    for (int i = 0; i < 4; ++i)
#pragma unroll
      for (int j = 0; j < 4; ++j)
        acc[i][j] = __builtin_amdgcn_mfma_f32_16x16x32_f16(ha[i], fbh[j], acc[i][j], 0, 0, 0);
#pragma unroll
    for (int i = 0; i < 4; ++i)
#pragma unroll
      for (int j = 0; j < 4; ++j)
        acc[i][j] = __builtin_amdgcn_mfma_f32_16x16x32_f16(ha[i], fbl[j], acc[i][j], 0, 0, 0);
#pragma unroll
    for (int i = 0; i < 4; ++i)
#pragma unroll
      for (int j = 0; j < 4; ++j)
        acc[i][j] = __builtin_amdgcn_mfma_f32_16x16x32_f16(la[i], fbh[j], acc[i][j], 0, 0, 0);
  };

  const int kbeg = kz * 1024, kend = kbeg + 1024;  // 16 phase-pairs exact
  h8 a0h[4], a0l[4], a1h[4], a1l[4];
  LOADA(kbeg, a0h, a0l);
  STAGE(0, kbeg);
  __syncthreads();
  for (int k0 = kbeg; k0 < kend; k0 += 64) {
    // phase 0: prefetch k0+32 (regs A1 + LDS buf1), compute k0 (A0, buf0)
    if (k0 + 32 < kend) { LOADA(k0 + 32, a1h, a1l); STAGE(1, k0 + 32); }
    COMPUTE(lds, a0h, a0l);
    __syncthreads();
    // phase 1: prefetch k0+64 (A0, buf0), compute k0+32 (A1, buf1)
    if (k0 + 64 < kend) { LOADA(k0 + 64, a0h, a0l); STAGE(0, k0 + 64); }
    COMPUTE(lds + 16384, a1h, a1l);
    __syncthreads();
  }
  float* Pz = P + (size_t)kz * PSLAB;
  const int prow = (lane >> 4) * 4;
#pragma unroll
  for (int i = 0; i < 4; ++i) {
#pragma unroll
    for (int j = 0; j < 4; ++j) {
      int n = n0 + wn + j * 16 + lrow;
#pragma unroll
      for (int r = 0; r < 4; ++r) {
        int m = m0 + wm + i * 16 + prow + r;
        Pz[(size_t)m * 2048 + n] = acc[i][j][r];
      }
    }
  }
}

// ---------------- split-K reduce: C = relu((p0+p1+p2)*RSCALE + bias) --------
// WRITE_SPLIT: also emit h/l f16 split (ASCALE) incl. zeroed rows 1568..1663.
template <int WRITE_SPLIT>
__global__ __launch_bounds__(256) void bb_reduce(const float* __restrict__ P,
                                                 const float* __restrict__ bias,
                                                 float* __restrict__ raw,
                                                 _Float16* __restrict__ h,
                                                 _Float16* __restrict__ l) {
  int idx = blockIdx.x * 256 + threadIdx.x;
  int m = idx >> 8, col = (idx & 255) * 8;
  if (WRITE_SPLIT) {
    if (m >= 1664) return;
    if (m >= 1568) {
      h8 z = {};
      *(h8*)(h + (size_t)m * 2048 + col) = z;
      *(h8*)(l + (size_t)m * 2048 + col) = z;
      return;
    }
  } else {
    if (m >= 1568) return;
  }
  size_t o = (size_t)m * 2048 + col;
  float v[8];
#pragma unroll
  for (int q = 0; q < 2; ++q) {
    float4 s0 = *(const float4*)(P + o + q * 4);
    float4 s1 = *(const float4*)(P + PSLAB + o + q * 4);
    float4 s2 = *(const float4*)(P + 2 * PSLAB + o + q * 4);
    float4 b = *(const float4*)(bias + col + q * 4);
    v[q * 4 + 0] = fmaxf(fmaf(s0.x + s1.x + s2.x, RSCALE, b.x), 0.f);
    v[q * 4 + 1] = fmaxf(fmaf(s0.y + s1.y + s2.y, RSCALE, b.y), 0.f);
    v[q * 4 + 2] = fmaxf(fmaf(s0.z + s1.z + s2.z, RSCALE, b.z), 0.f);
    v[q * 4 + 3] = fmaxf(fmaf(s0.w + s1.w + s2.w, RSCALE, b.w), 0.f);
  }
  *(float4*)(raw + o) = make_float4(v[0], v[1], v[2], v[3]);
  *(float4*)(raw + o + 4) = make_float4(v[4], v[5], v[6], v[7]);
  if (WRITE_SPLIT) {
    h8 vh, vl;
#pragma unroll
    for (int j = 0; j < 8; ++j) {
      float s = v[j] * ASCALE;
      _Float16 a = (_Float16)s;
      vh[j] = a; vl[j] = (_Float16)(s - (float)a);
    }
    *(h8*)(h + o) = vh;
    *(h8*)(l + o) = vl;
  }
}

// ---------------- navigator y1 GEMM: A reg-pipelined (im2col), B LDS-dbuf ---
__global__ __launch_bounds__(256, 2) void gemm_nav_mfma(
    const _Float16* __restrict__ Ah, const _Float16* __restrict__ Al,
    const _Float16* __restrict__ Bh, const _Float16* __restrict__ Bl,
    float* __restrict__ part) {
  __shared__ __align__(16) char lds[32768];
  const int t = threadIdx.x;
  // XCD-chunked bijective swizzle: 416 blocks = 8 XCD x 52.
  const int bid = blockIdx.x + 13 * blockIdx.y;
  const int orig = (bid & 7) * 52 + (bid >> 3);
  const int m0 = (orig % 13) * 128;
  const int sp = orig / 13;  // 0..31
  const int lane = t & 63, w = t >> 6;
  const int wm = (w >> 1) * 64, wn = (w & 1) * 64;
  const int lrow = lane & 15, kg = lane >> 4, kg8 = kg * 8;

  int offB[4];
#pragma unroll
  for (int i = 0; i < 4; ++i) {
    int bb2 = (wn + i * 16 + lrow) * 64 + kg * 16;
    offB[i] = bb2 ^ (((bb2 >> 7) & 3) << 4);
  }
  // Per-fragment im2col row state (4 rows per thread).
  int fb[4], fpy[4], fpx[4], fvalid[4];
#pragma unroll
  for (int i = 0; i < 4; ++i) {
    int m = m0 + wm + i * 16 + lrow;
    fvalid[i] = (m < 1568);
    int b = m / 196, pos = m % 196;
    fb[i] = b; fpy[i] = pos / 14; fpx[i] = pos % 14;
  }

  size_t gBo[2];
  int ldso[2];
#pragma unroll
  for (int e = 0; e < 2; ++e) {
    int p = e * 256 + t;
    int lsl = p ^ ((p >> 3) & 3);
    int row = lsl >> 2, kq = lsl & 3;
    gBo[e] = (size_t)row * 18432 + kq * 8;
    ldso[e] = e * 4096 + (t & 192) * 16;
  }

  auto LOADA = [&](int k0, h8 (&ha)[4], h8 (&la)[4]) {
    const int tap = k0 >> 11;   // 32 | 2048: no tap straddle within a K-step
    const int c = k0 & 2047;
    const int dy = tap / 3 - 1, dx = tap % 3 - 1;
#pragma unroll
    for (int i = 0; i < 4; ++i) {
      int sy = fpy[i] + dy, sx = fpx[i] + dx;
      bool ok = fvalid[i] && ((unsigned)sy < 14u) && ((unsigned)sx < 14u);
      size_t rowi = ok ? (size_t)(fb[i] * 196 + sy * 14 + sx) : (size_t)1600;
      size_t ao = rowi * 2048 + c + kg8;
      ha[i] = *(const h8*)(Ah + ao);
      la[i] = *(const h8*)(Al + ao);
    }
  };
  auto STAGE = [&](int buf, int k0) {
    char* L = lds + buf * 16384;
#pragma unroll
    for (int e = 0; e < 2; ++e) {
      gload16(Bh + gBo[e] + k0, L + ldso[e]);
      gload16(Bl + gBo[e] + k0, L + 8192 + ldso[e]);
    }
  };

  f32x4 acc[4][4] = {};
  auto COMPUTE = [&](const char* L, h8 (&ha)[4], h8 (&la)[4]) {
    h8 fbh[4], fbl[4];
#pragma unroll
    for (int j = 0; j < 4; ++j) {
      fbh[j] = *(const h8*)(L + offB[j]);
      fbl[j] = *(const h8*)(L + 8192 + offB[j]);
    }
#pragma unroll
    for (int i = 0; i < 4; ++i)
#pragma unroll
      for (int j = 0; j < 4; ++j)
        acc[i][j] = __builtin_amdgcn_mfma_f32_16x16x32_f16(ha[i], fbh[j], acc[i][j], 0, 0, 0);
#pragma unroll
    for (int i = 0; i < 4; ++i)
#pragma unroll
      for (int j = 0; j < 4; ++j)
        acc[i][j] = __builtin_amdgcn_mfma_f32_16x16x32_f16(ha[i], fbl[j], acc[i][j], 0, 0, 0);
#pragma unroll
    for (int i = 0; i < 4; ++i)
#pragma unroll
      for (int j = 0; j < 4; ++j)
        acc[i][j] = __builtin_amdgcn_mfma_f32_16x16x32_f16(la[i], fbh[j], acc[i][j], 0, 0, 0);
  };

  const int kbeg = sp * 576, kend = kbeg + 576;  // 9 phase-pairs exact
  h8 a0h[4], a0l[4], a1h[4], a1l[4];
  LOADA(kbeg, a0h, a0l);
  STAGE(0, kbeg);
  __syncthreads();
  for (int k0 = kbeg; k0 < kend; k0 += 64) {
    if (k0 + 32 < kend) { LOADA(k0 + 32, a1h, a1l); STAGE(1, k0 + 32); }
    COMPUTE(lds, a0h, a0l);
    __syncthreads();
    if (k0 + 64 < kend) { LOADA(k0 + 64, a0h, a0l); STAGE(0, k0 + 64); }
    COMPUTE(lds + 16384, a1h, a1l);
    __syncthreads();
  }
  const int prow = (lane >> 4) * 4;
#pragma unroll
  for (int i = 0; i < 4; ++i) {
#pragma unroll
    for (int j = 0; j < 4; ++j) {
      int n = wn + j * 16 + lrow;
#pragma unroll
      for (int r = 0; r < 4; ++r) {
        int m = m0 + wm + i * 16 + prow + r;
        if (m < 1568)
          part[((size_t)sp * 1568 + m) * 128 + n] = acc[i][j][r] * RSCALE;
      }
    }
  }
}

__global__ __launch_bounds__(256) void y1_reduce(const float* __restrict__ part,
                                                 const float* __restrict__ b1,
                                                 float* __restrict__ y1) {
  int idx = blockIdx.x * 256 + threadIdx.x;
  if (idx >= 1568 * 128) return;
  int o = idx & 127;
  float s = b1[o];
#pragma unroll
  for (int sp = 0; sp < 32; ++sp) s += part[(size_t)sp * 1568 * 128 + idx];
  y1[idx] = fmaxf(s, 0.f);
}

// ---------------- small 3x3 stride-2 pad-1 convs (128->128 ch, NHWC) --------
__global__ __launch_bounds__(256) void conv3x3s2(const float* __restrict__ in,
                                                 const float* __restrict__ wp,
                                                 const float* __restrict__ bias,
                                                 float* __restrict__ out,
                                                 int Hin, int Hout) {
  int idx = blockIdx.x * 256 + threadIdx.x;
  int total = 8 * Hout * Hout * 128;
  if (idx >= total) return;
  int o = idx & 127; int pos = idx >> 7;
  int ox = pos % Hout; int t2 = pos / Hout; int oy = t2 % Hout; int b = t2 / Hout;
  float acc = bias[o];
  for (int dy = 0; dy < 3; ++dy) {
    int iy = 2 * oy - 1 + dy;
    if (iy < 0 || iy >= Hin) continue;
    for (int dx = 0; dx < 3; ++dx) {
      int ix = 2 * ox - 1 + dx;
      if (ix < 0 || ix >= Hin) continue;
      const float* ip = in + ((b * Hin + iy) * Hin + ix) * 128;
      const float* wgt = wp + (o * 9 + dy * 3 + dx) * 128;
#pragma unroll 4
      for (int c = 0; c < 128; c += 4) {
        float4 a = *(const float4*)(ip + c);
        float4 ww = *(const float4*)(wgt + c);
        acc += a.x * ww.x + a.y * ww.y + a.z * ww.z + a.w * ww.w;
      }
    }
  }
  out[idx] = fmaxf(acc, 0.f);
}

// ---------------- rpn scores ------------------------------------------------
__global__ __launch_bounds__(256) void scores_kernel(
    const float* __restrict__ y1, const float* __restrict__ y2,
    const float* __restrict__ y3, const float* __restrict__ t1w,
    const float* __restrict__ t1b, const float* __restrict__ t2w,
    const float* __restrict__ t2b, const float* __restrict__ t3w,
    const float* __restrict__ t3b, float* __restrict__ scores) {
  int idx = blockIdx.x * 256 + threadIdx.x;
  if (idx >= 8 * 1614) return;
  int b = idx / 1614, sI = idx % 1614;
  const float* f; const float* w; float bias;
  if (sI < 1176) {
    int a = sI / 196;
    f = y1 + (b * 196 + (sI % 196)) * 128; w = t1w + a * 128; bias = t1b[a];
  } else if (sI < 1470) {
    int r = sI - 1176; int a = r / 49;
    f = y2 + (b * 49 + (r % 49)) * 128; w = t2w + a * 128; bias = t2b[a];
  } else {
    int r = sI - 1470; int a = r / 16;
    f = y3 + (b * 16 + (r % 16)) * 128; w = t3w + a * 128; bias = t3b[a];
  }
  float acc = 0.f;
  for (int c = 0; c < 128; c += 4) {
    float4 a4 = *(const float4*)(f + c);
    float4 w4 = *(const float4*)(w + c);
    acc += a4.x * w4.x + a4.y * w4.y + a4.z * w4.z + a4.w * w4.w;
  }
  scores[idx] = acc + bias;
}

// ---------------- greedy NMS (per batch block) ------------------------------
__global__ __launch_bounds__(256) void nms_kernel(const float* __restrict__ scores,
                                                  const int* __restrict__ anch,
                                                  const float* __restrict__ areas,
                                                  int* __restrict__ boxes) {
  const int b = blockIdx.x, t = threadIdx.x;
  const float* s = scores + b * 1614;
  __shared__ unsigned char valid[1614];
  __shared__ float rv[256];
  __shared__ int ri[256];
  for (int i = t; i < 1614; i += 256) valid[i] = 1;
  __syncthreads();
  for (int n = 0; n < 4; ++n) {
    float best = -INFINITY; int bi = 0x7fffffff;
    for (int i = t; i < 1614; i += 256) {
      if (valid[i]) {
        float v = s[i];
        if (v > best || (v == best && i < bi)) { best = v; bi = i; }
      }
    }
    rv[t] = best; ri[t] = bi;
    __syncthreads();
    for (int off = 128; off > 0; off >>= 1) {
      if (t < off) {
        float ov = rv[t + off]; int oi = ri[t + off];
        if (ov > rv[t] || (ov == rv[t] && oi < ri[t])) { rv[t] = ov; ri[t] = oi; }
      }
      __syncthreads();
    }
    int sel = ri[0];
    if (sel > 1613) sel = 0;
    const int4 bb = ((const int4*)anch)[sel];
    const float Ai = areas[sel];
    if (t == 0) ((int4*)boxes)[b * 4 + n] = bb;
    __syncthreads();
    for (int i = t; i < 1614; i += 256) {
      if (!valid[i]) continue;
      const int4 ab = ((const int4*)anch)[i];
      float sy = fmaxf((float)ab.x, (float)bb.x);
      float sx = fmaxf((float)ab.y, (float)bb.y);
      float ey = fminf((float)ab.z, (float)bb.z);
      float ex = fminf((float)ab.w, (float)bb.w);
      float ly = ey - sy, lx = ex - sx;
      float inter = (ly < 0.f || lx < 0.f) ? 0.f : ly * lx;
      float iou = inter / (areas[i] + Ai - inter);
      if (iou >= 0.25f) valid[i] = 0;
    }
    __syncthreads();
  }
}

// ---------------- bilinear crop -> A hi/lo (im2col layout, scaled) ----------
__global__ __launch_bounds__(256) void crop_kernel(const float* __restrict__ x,
                                                   const int* __restrict__ boxes,
                                                   _Float16* __restrict__ Ah,
                                                   _Float16* __restrict__ Al) {
  int idx = blockIdx.x * 256 + threadIdx.x;
  if (idx >= 32 * 3 * 224 * 224) return;
  int px = idx % 224; int t1 = idx / 224; int py = t1 % 224; int t2 = t1 / 224;
  int c = t2 % 3; int p = t2 / 3;
  int b = p >> 2;
  const int4 bb = ((const int4*)boxes)[p];
  float ty = (float)py / 223.0f;
  float txf = (float)px / 223.0f;
  float ys = (float)bb.x + ty * (float)(bb.z - bb.x - 1);
  float xs = (float)bb.y + txf * (float)(bb.w - bb.y - 1);
  float yf = floorf(ys), xf = floorf(xs);
  float wy = ys - yf, wx = xs - xf;
  int yl = (int)yf, xl = (int)xf;
  int yh = min(yl + 1, 895), xh = min(xl + 1, 895);
  const float* img = x + (size_t)(b * 3 + c) * 448 * 448;
  auto samp = [&](int yy, int xx) -> float {
    yy -= 224; xx -= 224;
    if (yy < 0 || yy >= 448 || xx < 0 || xx >= 448) return 0.f;
    return img[yy * 448 + xx];
  };
  float v00 = samp(yl, xl), v01 = samp(yl, xh);
  float v10 = samp(yh, xl), v11 = samp(yh, xh);
  float top = v00 * (1.f - wx) + v01 * wx;
  float bot = v10 * (1.f - wx) + v11 * wx;
  float val = top * (1.f - wy) + bot * wy;
  int i = py >> 5, r = py & 31, j = px >> 5, col = px & 31;
  int m = p * 49 + i * 7 + j;
  int k = (c << 10) + (r << 5) + col;
  float s = val * ASCALE;
  _Float16 a = (_Float16)s;
  Ah[(size_t)m * 3072 + k] = a;
  Al[(size_t)m * 3072 + k] = (_Float16)(s - (float)a);
}

// ---------------- row-parallel spatial mean ----------------------------------
// grid = groups * 32; block = 64 cols x 4 row-lanes.
__global__ __launch_bounds__(256) void mean_kernel(const float* __restrict__ in,
                                                   float* __restrict__ out,
                                                   int rows) {
  int g = blockIdx.x >> 5, chunk = blockIdx.x & 31;
  int col = chunk * 64 + (threadIdx.x & 63), rl = threadIdx.x >> 6;
  const float* base = in + ((size_t)g * rows) * 2048 + col;
  float s = 0.f;
  for (int r = rl; r < rows; r += 4) s += base[(size_t)r * 2048];
  __shared__ float red[4][64];
  red[rl][threadIdx.x & 63] = s;
  __syncthreads();
  if (rl == 0) {
    int c = threadIdx.x & 63;
    out[(size_t)g * 2048 + col] =
        ((red[0][c] + red[1][c]) + (red[2][c] + red[3][c])) / (float)rows;
  }
}

// ---------------- final linear: one wave per (b, class) ---------------------
__global__ __launch_bounds__(256) void final_kernel(const float* __restrict__ pfeat,
                                                    const float* __restrict__ rfeat,
                                                    const float* __restrict__ cw,
                                                    const float* __restrict__ cb,
                                                    float* __restrict__ out) {
  int gw = (blockIdx.x * 256 + threadIdx.x) >> 6;
  int lane = threadIdx.x & 63;
  if (gw >= 1600) return;
  int b = gw / 200, j = gw % 200;
  const float* wr = cw + (size_t)j * 10240;
  const float* pf = pfeat + (size_t)b * 8192;
  float acc = 0.f;
  for (int k = lane * 4; k < 8192; k += 256) {
    float4 a = *(const float4*)(pf + k);
    float4 w = *(const float4*)(wr + k);
    acc += a.x * w.x + a.y * w.y + a.z * w.z + a.w * w.w;
  }
  const float* rf = rfeat + (size_t)b * 2048;
  const float* wr2 = wr + 8192;
  for (int k = lane * 4; k < 2048; k += 256) {
    float4 a = *(const float4*)(rf + k);
    float4 w = *(const float4*)(wr2 + k);
    acc += a.x * w.x + a.y * w.y + a.z * w.z + a.w * w.w;
  }
#pragma unroll
  for (int off = 32; off > 0; off >>= 1) acc += __shfl_down(acc, off, 64);
  if (lane == 0) out[b * 200 + j] = acc + cb[j];
}

// ---------------------------------------------------------------------------
extern "C" void kernel_launch(void* const* d_in, const int* in_sizes, int n_in,
                              void* d_out, int out_size, void* d_ws, size_t ws_size,
                              hipStream_t stream) {
  const float* x   = (const float*)d_in[0];
  const float* bbw = (const float*)d_in[1];
  const float* bbb = (const float*)d_in[2];
  const float* w1  = (const float*)d_in[3];
  const float* b1  = (const float*)d_in[4];
  const float* t1w = (const float*)d_in[5];
  const float* t1b = (const float*)d_in[6];
  const float* w2  = (const float*)d_in[7];
  const float* b2  = (const float*)d_in[8];
  const float* t2w = (const float*)d_in[9];
  const float* t2b = (const float*)d_in[10];
  const float* w3  = (const float*)d_in[11];
  const float* b3  = (const float*)d_in[12];
  const float* t3w = (const float*)d_in[13];
  const float* t3b = (const float*)d_in[14];
  const float* cw  = (const float*)d_in[15];
  const float* cb  = (const float*)d_in[16];
  float* out = (float*)d_out;

  char* p = (char*)d_ws;
  auto alloc = [&](size_t bytes) -> char* {
    char* r = p; p += (bytes + 255) & ~(size_t)255; return r;
  };
  int*      anch  = (int*)     alloc((size_t)1614 * 4 * 4);
  float*    areas = (float*)   alloc((size_t)1614 * 4);
  _Float16* bWh   = (_Float16*)alloc((size_t)2048 * 3072 * 2);
  _Float16* bWl   = (_Float16*)alloc((size_t)2048 * 3072 * 2);
  _Float16* w1h   = (_Float16*)alloc((size_t)128 * 18432 * 2);
  _Float16* w1l   = (_Float16*)alloc((size_t)128 * 18432 * 2);
  _Float16* Ahh   = (_Float16*)alloc((size_t)1664 * 3072 * 2);
  _Float16* All   = (_Float16*)alloc((size_t)1664 * 3072 * 2);
  _Float16* rawh  = (_Float16*)alloc((size_t)1664 * 2048 * 2);
  _Float16* rawl  = (_Float16*)alloc((size_t)1664 * 2048 * 2);
  float*    raw   = (float*)   alloc((size_t)1568 * 2048 * 4);
  float*    w2p   = (float*)   alloc((size_t)128 * 9 * 128 * 4);
  float*    w3p   = (float*)   alloc((size_t)128 * 9 * 128 * 4);
  // P (split-K=3 partials) aliases y1s (32x1568x128 f32): disjoint lifetimes.
  char*     big   = alloc((size_t)4 * PSLAB * 4);
  float*    Pbuf  = (float*)big;
  float*    y1s   = (float*)big;
  float*    y1v   = (float*)   alloc((size_t)1568 * 128 * 4);
  float*    y2v   = (float*)   alloc((size_t)392 * 128 * 4);
  float*    y3v   = (float*)   alloc((size_t)128 * 128 * 4);
  float*    sc    = (float*)   alloc((size_t)8 * 1614 * 4);
  int*      boxes = (int*)     alloc((size_t)8 * 4 * 4 * 4);
  float*    pfeat = (float*)   alloc((size_t)32 * 2048 * 4);
  float*    rfeat = (float*)   alloc((size_t)8 * 2048 * 4);

  prep_small<<<7 + 576 + 576, 256, 0, stream>>>(anch, areas, w2, w2p, w3, w3p);
  split_w<<<(2048 * 3072 / 8 + 255) / 256, 256, 0, stream>>>(bbw, bWh, bWl, 2048 * 3072 / 8);
  split_w1<<<(128 * 9 * 2048 + 255) / 256, 256, 0, stream>>>(w1, w1h, w1l);
  split_x<<<(1664 * 384 + 255) / 256, 256, 0, stream>>>(x, Ahh, All);

  gemm_bb_mfma<<<dim3(13, 16, 3), 256, 0, stream>>>(Ahh, All, bWh, bWl, Pbuf);
  bb_reduce<1><<<1664, 256, 0, stream>>>(Pbuf, bbb, raw, rawh, rawl);
  gemm_nav_mfma<<<dim3(13, 32), 256, 0, stream>>>(rawh, rawl, w1h, w1l, y1s);
  y1_reduce<<<(1568 * 128 + 255) / 256, 256, 0, stream>>>(y1s, b1, y1v);
  mean_kernel<<<8 * 32, 256, 0, stream>>>(raw, rfeat, 196);
  conv3x3s2<<<(8 * 7 * 7 * 128 + 255) / 256, 256, 0, stream>>>(y1v, w2p, b2, y2v, 14, 7);
  conv3x3s2<<<(8 * 4 * 4 * 128 + 255) / 256, 256, 0, stream>>>(y2v, w3p, b3, y3v, 7, 4);
  scores_kernel<<<(8 * 1614 + 255) / 256, 256, 0, stream>>>(
      y1v, y2v, y3v, t1w, t1b, t2w, t2b, t3w, t3b, sc);
  nms_kernel<<<8, 256, 0, stream>>>(sc, anch, areas, boxes);
  crop_kernel<<<(32 * 3 * 224 * 224) / 256, 256, 0, stream>>>(x, boxes, Ahh, All);
  gemm_bb_mfma<<<dim3(13, 16, 3), 256, 0, stream>>>(Ahh, All, bWh, bWl, Pbuf);
  bb_reduce<0><<<1568, 256, 0, stream>>>(Pbuf, bbb, raw, rawh, rawl);
  mean_kernel<<<32 * 32, 256, 0, stream>>>(raw, pfeat, 49);
  final_kernel<<<400, 256, 0, stream>>>(pfeat, rfeat, cw, cb, out);
}

// Round 10
// 372.937 us; speedup vs baseline: 2.4230x; 1.3934x over previous
//
#include <hip/hip_runtime.h>
#include <math.h>

// ---------------------------------------------------------------------------
// NTSNet forward. Big GEMMs on MFMA via 2-way f16 split (3 products: hh,hl,lh)
// R2: parallel means. R3: split-K. R4: 2-phase dbuf + XCD swizzle (77us, the
// best measured GEMM). R5: fused prep. R6/R7/R8: A-path restructures ALL
// REGRESSED (same-iter latency / spills / L2 thrash). R9: revert GEMMs to the
// R4/R5-proven form (split-K=2); fuse split-K reduce + spatial mean into
// feat_reduce (pfeat/rfeat direct from P partials); drop raw f32 buffer.
// ---------------------------------------------------------------------------

typedef _Float16 h8 __attribute__((ext_vector_type(8)));
typedef float f32x4 __attribute__((ext_vector_type(4)));

#define ASCALE 256.0f
#define WSCALE 16384.0f
#define RSCALE (1.0f / (256.0f * 16384.0f))
#define PSLAB ((size_t)1664 * 2048)

__device__ __forceinline__ void gload16(const void* g, void* l) {
  __builtin_amdgcn_global_load_lds(
      (__attribute__((address_space(1))) void*)(void*)(uintptr_t)g,
      (__attribute__((address_space(3))) void*)l, 16, 0, 0);
}

// ---------------- merged small prep: anchors + w2/w3 permutes ---------------
__device__ void anchors_body(int i, int* anch, float* areas) {
  if (i >= 1614) return;
  int stride, oh, a, pos;
  double size, sc;
  const double C13 = 1.2599210498948732;
  const double C23 = 1.5874010519681994;
  if (i < 1176) {
    stride = 32; size = 48.0; oh = 14; a = i / 196; pos = i % 196;
    sc = (a / 3 == 0) ? C13 : C23;
  } else if (i < 1470) {
    int r = i - 1176; stride = 64; size = 96.0; oh = 7; a = r / 49; pos = r % 49;
    sc = (a / 3 == 0) ? C13 : C23;
  } else {
    int r = i - 1470; stride = 128; size = 192.0; oh = 4; a = r / 16; pos = r % 16;
    int si = a / 3;
    sc = (si == 0) ? 1.0 : ((si == 1) ? C13 : C23);
  }
  int ari = a % 3;
  double ar = (ari == 0) ? 0.667 : ((ari == 1) ? 1.0 : 1.5);
  int gy = pos / oh, gx = pos % oh;
  float cy = 0.5f * (float)stride + (float)(stride * gy);
  float cx = 0.5f * (float)stride + (float)(stride * gx);
  double ss = sqrt(ar);
  double hd = (size * sc) / ss;
  double wd = (size * sc) * ss;
  float hh = (float)(hd * 0.5), wh = (float)(wd * 0.5);
  int y0 = (int)((cy - hh) + 224.0f), x0 = (int)((cx - wh) + 224.0f);
  int y1i = (int)((cy + hh) + 224.0f), x1i = (int)((cx + wh) + 224.0f);
  anch[i * 4 + 0] = y0; anch[i * 4 + 1] = x0;
  anch[i * 4 + 2] = y1i; anch[i * 4 + 3] = x1i;
  areas[i] = (float)(y1i - y0) * (float)(x1i - x0);
}

__global__ __launch_bounds__(256) void prep_small(int* __restrict__ anch,
                                                  float* __restrict__ areas,
                                                  const float* __restrict__ w2,
                                                  float* __restrict__ w2p,
                                                  const float* __restrict__ w3,
                                                  float* __restrict__ w3p) {
  int b = blockIdx.x, t = threadIdx.x;
  if (b < 7) { anchors_body(b * 256 + t, anch, areas); return; }
  const float* src; float* dst; int idx;
  if (b < 7 + 576) { src = w2; dst = w2p; idx = (b - 7) * 256 + t; }
  else             { src = w3; dst = w3p; idx = (b - 583) * 256 + t; }
  if (idx >= 128 * 9 * 128) return;
  int c = idx % 128; int r2 = idx / 128; int tap = r2 % 9; int o = r2 / 9;
  dst[idx] = src[(o * 128 + c) * 9 + tap];
}

// ---------------- f32 -> f16 hi/lo split (linear, scale WSCALE) -------------
__global__ __launch_bounds__(256) void split_w(const float* __restrict__ src,
                                               _Float16* __restrict__ h,
                                               _Float16* __restrict__ l, int n8) {
  int i = blockIdx.x * 256 + threadIdx.x;
  if (i >= n8) return;
  float4 v0 = *(const float4*)(src + (size_t)i * 8);
  float4 v1 = *(const float4*)(src + (size_t)i * 8 + 4);
  float vv[8] = {v0.x, v0.y, v0.z, v0.w, v1.x, v1.y, v1.z, v1.w};
  h8 vh, vl;
#pragma unroll
  for (int j = 0; j < 8; ++j) {
    float s = vv[j] * WSCALE;
    _Float16 a = (_Float16)s;
    vh[j] = a; vl[j] = (_Float16)(s - (float)a);
  }
  *(h8*)(h + (size_t)i * 8) = vh;
  *(h8*)(l + (size_t)i * 8) = vl;
}

// ---------------- fused w1 permute + split: h/l[o][tap][c] from w1[o][c][tap]
__global__ __launch_bounds__(256) void split_w1(const float* __restrict__ w1,
                                                _Float16* __restrict__ h,
                                                _Float16* __restrict__ l) {
  int idx = blockIdx.x * 256 + threadIdx.x;
  if (idx >= 128 * 9 * 2048) return;
  int c = idx & 2047; int rest = idx >> 11; int tap = rest % 9; int o = rest / 9;
  float v = w1[(o * 2048 + c) * 9 + tap] * WSCALE;
  _Float16 a = (_Float16)v;
  h[idx] = a; l[idx] = (_Float16)(v - (float)a);
}

// ---------------- x patchify -> A hi/lo [1664][3072] (scale ASCALE) ---------
__global__ __launch_bounds__(256) void split_x(const float* __restrict__ x,
                                               _Float16* __restrict__ Ah,
                                               _Float16* __restrict__ Al) {
  int i = blockIdx.x * 256 + threadIdx.x;
  if (i >= 1664 * 384) return;
  int kq = i % 384, m = i / 384;
  int k = kq * 8;
  h8 vh = {}, vl = {};
  if (m < 1568) {
    int b = m / 196, pos = m % 196;
    int c = k >> 10, r = (k >> 5) & 31, col = k & 31;
    int py = (pos / 14) * 32 + r, px = (pos % 14) * 32 + col;
    const float* sp2 = x + (((size_t)(b * 3 + c) * 448 + py) * 448 + px);
    float4 v0 = *(const float4*)sp2;
    float4 v1 = *(const float4*)(sp2 + 4);
    float vv[8] = {v0.x, v0.y, v0.z, v0.w, v1.x, v1.y, v1.z, v1.w};
#pragma unroll
    for (int j = 0; j < 8; ++j) {
      float s = vv[j] * ASCALE;
      _Float16 a = (_Float16)s;
      vh[j] = a; vl[j] = (_Float16)(s - (float)a);
    }
  }
  *(h8*)(Ah + (size_t)m * 3072 + k) = vh;
  *(h8*)(Al + (size_t)m * 3072 + k) = vl;
}

// ---------------- backbone GEMM (R4-proven: 4-tensor LDS dbuf, split-K=2) ---
// Writes raw f32 dot-product partials P[z][1664][2048] (no scale/bias).
__global__ __launch_bounds__(256) void gemm_bb_mfma(
    const _Float16* __restrict__ Ah, const _Float16* __restrict__ Al,
    const _Float16* __restrict__ Bh, const _Float16* __restrict__ Bl,
    float* __restrict__ P) {
  __shared__ __align__(16) char lds[65536];  // 2 x (Ah|Al|Bh|Bl tiles, 8KB each)
  const int t = threadIdx.x;
  // XCD-chunked bijective swizzle: 208 xy-blocks = 8 XCD x 26.
  const int bid = blockIdx.x + 13 * blockIdx.y;
  const int orig = (bid & 7) * 26 + (bid >> 3);
  const int m0 = (orig % 13) * 128, n0 = (orig / 13) * 128;
  const int kz = blockIdx.z;
  const int lane = t & 63, w = t >> 6;
  const int wm = (w >> 1) * 64, wn = (w & 1) * 64;
  const int lrow = lane & 15, kg = lane >> 4;

  int offA[4], offB[4];
#pragma unroll
  for (int i = 0; i < 4; ++i) {
    int ba = (wm + i * 16 + lrow) * 64 + kg * 16;
    offA[i] = ba ^ (((ba >> 7) & 3) << 4);
    int bb2 = (wn + i * 16 + lrow) * 64 + kg * 16;
    offB[i] = bb2 ^ (((bb2 >> 7) & 3) << 4);
  }
  size_t gAo[2], gBo[2];
  int ldso[2];
#pragma unroll
  for (int e = 0; e < 2; ++e) {
    int p = e * 256 + t;
    int lsl = p ^ ((p >> 3) & 3);   // inverse swizzle (involution) in slot units
    int row = lsl >> 2, kq = lsl & 3;
    gAo[e] = (size_t)(m0 + row) * 3072 + kq * 8;
    gBo[e] = (size_t)(n0 + row) * 3072 + kq * 8;
    ldso[e] = e * 4096 + (t & 192) * 16;
  }

  auto STAGE = [&](int buf, int k0) {
    char* L = lds + buf * 32768;
#pragma unroll
    for (int e = 0; e < 2; ++e) {
      gload16(Ah + gAo[e] + k0, L + ldso[e]);
      gload16(Al + gAo[e] + k0, L + 8192 + ldso[e]);
      gload16(Bh + gBo[e] + k0, L + 16384 + ldso[e]);
      gload16(Bl + gBo[e] + k0, L + 24576 + ldso[e]);
    }
  };

  f32x4 acc[4][4] = {};
  const int kbeg = kz * 1536, kend = kbeg + 1536;
  STAGE(0, kbeg);
  __syncthreads();
  int cur = 0;
  for (int k0 = kbeg; k0 < kend; k0 += 32) {
    if (k0 + 32 < kend) STAGE(cur ^ 1, k0 + 32);  // issue-early: hides under MFMA
    const char* L = lds + cur * 32768;
    h8 fah[4], fal[4], fbh[4], fbl[4];
#pragma unroll
    for (int i = 0; i < 4; ++i) {
      fah[i] = *(const h8*)(L + offA[i]);
      fal[i] = *(const h8*)(L + 8192 + offA[i]);
      fbh[i] = *(const h8*)(L + 16384 + offB[i]);
      fbl[i] = *(const h8*)(L + 24576 + offB[i]);
    }
#pragma unroll
    for (int i = 0; i < 4; ++i)
#pragma unroll
      for (int j = 0; j < 4; ++j)
        acc[i][j] = __builtin_amdgcn_mfma_f32_16x16x32_f16(fah[i], fbh[j], acc[i][j], 0, 0, 0);
#pragma unroll
    for (int i = 0; i < 4; ++i)
#pragma unroll
      for (int j = 0; j < 4; ++j)
        acc[i][j] = __builtin_amdgcn_mfma_f32_16x16x32_f16(fah[i], fbl[j], acc[i][j], 0, 0, 0);
#pragma unroll
    for (int i = 0; i < 4; ++i)
#pragma unroll
      for (int j = 0; j < 4; ++j)
        acc[i][j] = __builtin_amdgcn_mfma_f32_16x16x32_f16(fal[i], fbh[j], acc[i][j], 0, 0, 0);
    __syncthreads();
    cur ^= 1;
  }
  float* Pz = P + (size_t)kz * PSLAB;
  const int prow = (lane >> 4) * 4;
#pragma unroll
  for (int i = 0; i < 4; ++i) {
#pragma unroll
    for (int j = 0; j < 4; ++j) {
      int n = n0 + wn + j * 16 + lrow;
#pragma unroll
      for (int r = 0; r < 4; ++r) {
        int m = m0 + wm + i * 16 + prow + r;
        Pz[(size_t)m * 2048 + n] = acc[i][j][r];
      }
    }
  }
}

// ---------------- split-K reduce -> f16 hi/lo split only (for nav input) ----
// relu((p0+p1)*RSCALE+bias), emit rawh/rawl (ASCALE) incl. zero rows 1568+.
__global__ __launch_bounds__(256) void bb_reduce_split(const float* __restrict__ P,
                                                       const float* __restrict__ bias,
                                                       _Float16* __restrict__ h,
                                                       _Float16* __restrict__ l) {
  int idx = blockIdx.x * 256 + threadIdx.x;
  int m = idx >> 8, col = (idx & 255) * 8;
  if (m >= 1664) return;
  size_t o = (size_t)m * 2048 + col;
  if (m >= 1568) {
    h8 z = {};
    *(h8*)(h + o) = z;
    *(h8*)(l + o) = z;
    return;
  }
  h8 vh, vl;
#pragma unroll
  for (int q = 0; q < 2; ++q) {
    float4 s0 = *(const float4*)(P + o + q * 4);
    float4 s1 = *(const float4*)(P + PSLAB + o + q * 4);
    float4 b = *(const float4*)(bias + col + q * 4);
    float v[4];
    v[0] = fmaxf(fmaf(s0.x + s1.x, RSCALE, b.x), 0.f);
    v[1] = fmaxf(fmaf(s0.y + s1.y, RSCALE, b.y), 0.f);
    v[2] = fmaxf(fmaf(s0.z + s1.z, RSCALE, b.z), 0.f);
    v[3] = fmaxf(fmaf(s0.w + s1.w, RSCALE, b.w), 0.f);
#pragma unroll
    for (int j = 0; j < 4; ++j) {
      float s = v[j] * ASCALE;
      _Float16 a = (_Float16)s;
      vh[q * 4 + j] = a; vl[q * 4 + j] = (_Float16)(s - (float)a);
    }
  }
  *(h8*)(h + o) = vh;
  *(h8*)(l + o) = vl;
}

// ---------------- fused split-K reduce + relu + spatial mean ----------------
// out[g][col] = mean_r relu((p0+p1)[g*rows+r][col]*RSCALE + bias[col]).
// grid = groups*32 (64-col chunks); block = 64 cols x 4 row-lanes.
__global__ __launch_bounds__(256) void feat_reduce(const float* __restrict__ P,
                                                   const float* __restrict__ bias,
                                                   float* __restrict__ out,
                                                   int rows) {
  int g = blockIdx.x >> 5, chunk = blockIdx.x & 31;
  int col = chunk * 64 + (threadIdx.x & 63), rl = threadIdx.x >> 6;
  const float* base0 = P + ((size_t)g * rows) * 2048 + col;
  const float* base1 = base0 + PSLAB;
  float bcol = bias[col];
  float s = 0.f;
  for (int r = rl; r < rows; r += 4)
    s += fmaxf(fmaf(base0[(size_t)r * 2048] + base1[(size_t)r * 2048], RSCALE, bcol), 0.f);
  __shared__ float red[4][64];
  red[rl][threadIdx.x & 63] = s;
  __syncthreads();
  if (rl == 0) {
    int c = threadIdx.x & 63;
    out[(size_t)g * 2048 + col] =
        ((red[0][c] + red[1][c]) + (red[2][c] + red[3][c])) / (float)rows;
  }
}

// ---------------- navigator y1 GEMM (R5-proven, split-K=32, 4-tensor dbuf) --
__global__ __launch_bounds__(256) void gemm_nav_mfma(
    const _Float16* __restrict__ Ah, const _Float16* __restrict__ Al,
    const _Float16* __restrict__ Bh, const _Float16* __restrict__ Bl,
    float* __restrict__ part) {
  __shared__ __align__(16) char lds[65536];
  const int t = threadIdx.x;
  // XCD-chunked bijective swizzle: 416 blocks = 8 XCD x 52.
  const int bid = blockIdx.x + 13 * blockIdx.y;
  const int orig = (bid & 7) * 52 + (bid >> 3);
  const int m0 = (orig % 13) * 128;
  const int sp = orig / 13;  // 0..31
  const int lane = t & 63, w = t >> 6;
  const int wm = (w >> 1) * 64, wn = (w & 1) * 64;
  const int lrow = lane & 15, kg = lane >> 4;

  int offA[4], offB[4];
#pragma unroll
  for (int i = 0; i < 4; ++i) {
    int ba = (wm + i * 16 + lrow) * 64 + kg * 16;
    offA[i] = ba ^ (((ba >> 7) & 3) << 4);
    int bb2 = (wn + i * 16 + lrow) * 64 + kg * 16;
    offB[i] = bb2 ^ (((bb2 >> 7) & 3) << 4);
  }
  size_t gBo[2];
  int ldso[2], akq8[2], ab[2], apy[2], apx[2], amv[2];
#pragma unroll
  for (int e = 0; e < 2; ++e) {
    int p = e * 256 + t;
    int lsl = p ^ ((p >> 3) & 3);
    int row = lsl >> 2, kq = lsl & 3;
    gBo[e] = (size_t)row * 18432 + kq * 8;
    ldso[e] = e * 4096 + (t & 192) * 16;
    int m = m0 + row;
    amv[e] = (m < 1568);
    int b = m / 196, pos = m % 196;
    ab[e] = b; apy[e] = pos / 14; apx[e] = pos % 14;
    akq8[e] = kq * 8;
  }

  auto STAGE = [&](int buf, int k0) {
    const int tap = k0 >> 11;   // 32 | 2048: no tap straddle within a K-step
    const int c = k0 & 2047;
    const int dy = tap / 3 - 1, dx = tap % 3 - 1;
    char* L = lds + buf * 32768;
#pragma unroll
    for (int e = 0; e < 2; ++e) {
      int sy = apy[e] + dy, sx = apx[e] + dx;
      bool ok = amv[e] && ((unsigned)sy < 14u) && ((unsigned)sx < 14u);
      size_t rowi = ok ? (size_t)(ab[e] * 196 + sy * 14 + sx) : (size_t)1600;
      size_t ao = rowi * 2048 + c + akq8[e];
      gload16(Ah + ao, L + ldso[e]);
      gload16(Al + ao, L + 8192 + ldso[e]);
      gload16(Bh + gBo[e] + k0, L + 16384 + ldso[e]);
      gload16(Bl + gBo[e] + k0, L + 24576 + ldso[e]);
    }
  };

  f32x4 acc[4][4] = {};
  const int kbeg = sp * 576, kend = kbeg + 576;
  STAGE(0, kbeg);
  __syncthreads();
  int cur = 0;
  for (int k0 = kbeg; k0 < kend; k0 += 32) {
    if (k0 + 32 < kend) STAGE(cur ^ 1, k0 + 32);
    const char* L = lds + cur * 32768;
    h8 fah[4], fal[4], fbh[4], fbl[4];
#pragma unroll
    for (int i = 0; i < 4; ++i) {
      fah[i] = *(const h8*)(L + offA[i]);
      fal[i] = *(const h8*)(L + 8192 + offA[i]);
      fbh[i] = *(const h8*)(L + 16384 + offB[i]);
      fbl[i] = *(const h8*)(L + 24576 + offB[i]);
    }
#pragma unroll
    for (int i = 0; i < 4; ++i)
#pragma unroll
      for (int j = 0; j < 4; ++j)
        acc[i][j] = __builtin_amdgcn_mfma_f32_16x16x32_f16(fah[i], fbh[j], acc[i][j], 0, 0, 0);
#pragma unroll
    for (int i = 0; i < 4; ++i)
#pragma unroll
      for (int j = 0; j < 4; ++j)
        acc[i][j] = __builtin_amdgcn_mfma_f32_16x16x32_f16(fah[i], fbl[j], acc[i][j], 0, 0, 0);
#pragma unroll
    for (int i = 0; i < 4; ++i)
#pragma unroll
      for (int j = 0; j < 4; ++j)
        acc[i][j] = __builtin_amdgcn_mfma_f32_16x16x32_f16(fal[i], fbh[j], acc[i][j], 0, 0, 0);
    __syncthreads();
    cur ^= 1;
  }
  const int prow = (lane >> 4) * 4;
#pragma unroll
  for (int i = 0; i < 4; ++i) {
#pragma unroll
    for (int j = 0; j < 4; ++j) {
      int n = wn + j * 16 + lrow;
#pragma unroll
      for (int r = 0; r < 4; ++r) {
        int m = m0 + wm + i * 16 + prow + r;
        if (m < 1568)
          part[((size_t)sp * 1568 + m) * 128 + n] = acc[i][j][r] * RSCALE;
      }
    }
  }
}

__global__ __launch_bounds__(256) void y1_reduce(const float* __restrict__ part,
                                                 const float* __restrict__ b1,
                                                 float* __restrict__ y1) {
  int idx = blockIdx.x * 256 + threadIdx.x;
  if (idx >= 1568 * 128) return;
  int o = idx & 127;
  float s = b1[o];
#pragma unroll
  for (int sp = 0; sp < 32; ++sp) s += part[(size_t)sp * 1568 * 128 + idx];
  y1[idx] = fmaxf(s, 0.f);
}

// ---------------- small 3x3 stride-2 pad-1 convs (128->128 ch, NHWC) --------
__global__ __launch_bounds__(256) void conv3x3s2(const float* __restrict__ in,
                                                 const float* __restrict__ wp,
                                                 const float* __restrict__ bias,
                                                 float* __restrict__ out,
                                                 int Hin, int Hout) {
  int idx = blockIdx.x * 256 + threadIdx.x;
  int total = 8 * Hout * Hout * 128;
  if (idx >= total) return;
  int o = idx & 127; int pos = idx >> 7;
  int ox = pos % Hout; int t2 = pos / Hout; int oy = t2 % Hout; int b = t2 / Hout;
  float acc = bias[o];
  for (int dy = 0; dy < 3; ++dy) {
    int iy = 2 * oy - 1 + dy;
    if (iy < 0 || iy >= Hin) continue;
    for (int dx = 0; dx < 3; ++dx) {
      int ix = 2 * ox - 1 + dx;
      if (ix < 0 || ix >= Hin) continue;
      const float* ip = in + ((b * Hin + iy) * Hin + ix) * 128;
      const float* wgt = wp + (o * 9 + dy * 3 + dx) * 128;
#pragma unroll 4
      for (int c = 0; c < 128; c += 4) {
        float4 a = *(const float4*)(ip + c);
        float4 ww = *(const float4*)(wgt + c);
        acc += a.x * ww.x + a.y * ww.y + a.z * ww.z + a.w * ww.w;
      }
    }
  }
  out[idx] = fmaxf(acc, 0.f);
}

// ---------------- rpn scores ------------------------------------------------
__global__ __launch_bounds__(256) void scores_kernel(
    const float* __restrict__ y1, const float* __restrict__ y2,
    const float* __restrict__ y3, const float* __restrict__ t1w,
    const float* __restrict__ t1b, const float* __restrict__ t2w,
    const float* __restrict__ t2b, const float* __restrict__ t3w,
    const float* __restrict__ t3b, float* __restrict__ scores) {
  int idx = blockIdx.x * 256 + threadIdx.x;
  if (idx >= 8 * 1614) return;
  int b = idx / 1614, sI = idx % 1614;
  const float* f; const float* w; float bias;
  if (sI < 1176) {
    int a = sI / 196;
    f = y1 + (b * 196 + (sI % 196)) * 128; w = t1w + a * 128; bias = t1b[a];
  } else if (sI < 1470) {
    int r = sI - 1176; int a = r / 49;
    f = y2 + (b * 49 + (r % 49)) * 128; w = t2w + a * 128; bias = t2b[a];
  } else {
    int r = sI - 1470; int a = r / 16;
    f = y3 + (b * 16 + (r % 16)) * 128; w = t3w + a * 128; bias = t3b[a];
  }
  float acc = 0.f;
  for (int c = 0; c < 128; c += 4) {
    float4 a4 = *(const float4*)(f + c);
    float4 w4 = *(const float4*)(w + c);
    acc += a4.x * w4.x + a4.y * w4.y + a4.z * w4.z + a4.w * w4.w;
  }
  scores[idx] = acc + bias;
}

// ---------------- greedy NMS (per batch block) ------------------------------
__global__ __launch_bounds__(256) void nms_kernel(const float* __restrict__ scores,
                                                  const int* __restrict__ anch,
                                                  const float* __restrict__ areas,
                                                  int* __restrict__ boxes) {
  const int b = blockIdx.x, t = threadIdx.x;
  const float* s = scores + b * 1614;
  __shared__ unsigned char valid[1614];
  __shared__ float rv[256];
  __shared__ int ri[256];
  for (int i = t; i < 1614; i += 256) valid[i] = 1;
  __syncthreads();
  for (int n = 0; n < 4; ++n) {
    float best = -INFINITY; int bi = 0x7fffffff;
    for (int i = t; i < 1614; i += 256) {
      if (valid[i]) {
        float v = s[i];
        if (v > best || (v == best && i < bi)) { best = v; bi = i; }
      }
    }
    rv[t] = best; ri[t] = bi;
    __syncthreads();
    for (int off = 128; off > 0; off >>= 1) {
      if (t < off) {
        float ov = rv[t + off]; int oi = ri[t + off];
        if (ov > rv[t] || (ov == rv[t] && oi < ri[t])) { rv[t] = ov; ri[t] = oi; }
      }
      __syncthreads();
    }
    int sel = ri[0];
    if (sel > 1613) sel = 0;
    const int4 bb = ((const int4*)anch)[sel];
    const float Ai = areas[sel];
    if (t == 0) ((int4*)boxes)[b * 4 + n] = bb;
    __syncthreads();
    for (int i = t; i < 1614; i += 256) {
      if (!valid[i]) continue;
      const int4 ab = ((const int4*)anch)[i];
      float sy = fmaxf((float)ab.x, (float)bb.x);
      float sx = fmaxf((float)ab.y, (float)bb.y);
      float ey = fminf((float)ab.z, (float)bb.z);
      float ex = fminf((float)ab.w, (float)bb.w);
      float ly = ey - sy, lx = ex - sx;
      float inter = (ly < 0.f || lx < 0.f) ? 0.f : ly * lx;
      float iou = inter / (areas[i] + Ai - inter);
      if (iou >= 0.25f) valid[i] = 0;
    }
    __syncthreads();
  }
}

// ---------------- bilinear crop -> A hi/lo (im2col layout, scaled) ----------
__global__ __launch_bounds__(256) void crop_kernel(const float* __restrict__ x,
                                                   const int* __restrict__ boxes,
                                                   _Float16* __restrict__ Ah,
                                                   _Float16* __restrict__ Al) {
  int idx = blockIdx.x * 256 + threadIdx.x;
  if (idx >= 32 * 3 * 224 * 224) return;
  int px = idx % 224; int t1 = idx / 224; int py = t1 % 224; int t2 = t1 / 224;
  int c = t2 % 3; int p = t2 / 3;
  int b = p >> 2;
  const int4 bb = ((const int4*)boxes)[p];
  float ty = (float)py / 223.0f;
  float txf = (float)px / 223.0f;
  float ys = (float)bb.x + ty * (float)(bb.z - bb.x - 1);
  float xs = (float)bb.y + txf * (float)(bb.w - bb.y - 1);
  float yf = floorf(ys), xf = floorf(xs);
  float wy = ys - yf, wx = xs - xf;
  int yl = (int)yf, xl = (int)xf;
  int yh = min(yl + 1, 895), xh = min(xl + 1, 895);
  const float* img = x + (size_t)(b * 3 + c) * 448 * 448;
  auto samp = [&](int yy, int xx) -> float {
    yy -= 224; xx -= 224;
    if (yy < 0 || yy >= 448 || xx < 0 || xx >= 448) return 0.f;
    return img[yy * 448 + xx];
  };
  float v00 = samp(yl, xl), v01 = samp(yl, xh);
  float v10 = samp(yh, xl), v11 = samp(yh, xh);
  float top = v00 * (1.f - wx) + v01 * wx;
  float bot = v10 * (1.f - wx) + v11 * wx;
  float val = top * (1.f - wy) + bot * wy;
  int i = py >> 5, r = py & 31, j = px >> 5, col = px & 31;
  int m = p * 49 + i * 7 + j;
  int k = (c << 10) + (r << 5) + col;
  float s = val * ASCALE;
  _Float16 a = (_Float16)s;
  Ah[(size_t)m * 3072 + k] = a;
  Al[(size_t)m * 3072 + k] = (_Float16)(s - (float)a);
}

// ---------------- final linear: one wave per (b, class) ---------------------
__global__ __launch_bounds__(256) void final_kernel(const float* __restrict__ pfeat,
                                                    const float* __restrict__ rfeat,
                                                    const float* __restrict__ cw,
                                                    const float* __restrict__ cb,
                                                    float* __restrict__ out) {
  int gw = (blockIdx.x * 256 + threadIdx.x) >> 6;
  int lane = threadIdx.x & 63;
  if (gw >= 1600) return;
  int b = gw / 200, j = gw % 200;
  const float* wr = cw + (size_t)j * 10240;
  const float* pf = pfeat + (size_t)b * 8192;
  float acc = 0.f;
  for (int k = lane * 4; k < 8192; k += 256) {
    float4 a = *(const float4*)(pf + k);
    float4 w = *(const float4*)(wr + k);
    acc += a.x * w.x + a.y * w.y + a.z * w.z + a.w * w.w;
  }
  const float* rf = rfeat + (size_t)b * 2048;
  const float* wr2 = wr + 8192;
  for (int k = lane * 4; k < 2048; k += 256) {
    float4 a = *(const float4*)(rf + k);
    float4 w = *(const float4*)(wr2 + k);
    acc += a.x * w.x + a.y * w.y + a.z * w.z + a.w * w.w;
  }
#pragma unroll
  for (int off = 32; off > 0; off >>= 1) acc += __shfl_down(acc, off, 64);
  if (lane == 0) out[b * 200 + j] = acc + cb[j];
}

// ---------------------------------------------------------------------------
extern "C" void kernel_launch(void* const* d_in, const int* in_sizes, int n_in,
                              void* d_out, int out_size, void* d_ws, size_t ws_size,
                              hipStream_t stream) {
  const float* x   = (const float*)d_in[0];
  const float* bbw = (const float*)d_in[1];
  const float* bbb = (const float*)d_in[2];
  const float* w1  = (const float*)d_in[3];
  const float* b1  = (const float*)d_in[4];
  const float* t1w = (const float*)d_in[5];
  const float* t1b = (const float*)d_in[6];
  const float* w2  = (const float*)d_in[7];
  const float* b2  = (const float*)d_in[8];
  const float* t2w = (const float*)d_in[9];
  const float* t2b = (const float*)d_in[10];
  const float* w3  = (const float*)d_in[11];
  const float* b3  = (const float*)d_in[12];
  const float* t3w = (const float*)d_in[13];
  const float* t3b = (const float*)d_in[14];
  const float* cw  = (const float*)d_in[15];
  const float* cb  = (const float*)d_in[16];
  float* out = (float*)d_out;

  char* p = (char*)d_ws;
  auto alloc = [&](size_t bytes) -> char* {
    char* r = p; p += (bytes + 255) & ~(size_t)255; return r;
  };
  int*      anch  = (int*)     alloc((size_t)1614 * 4 * 4);
  float*    areas = (float*)   alloc((size_t)1614 * 4);
  _Float16* bWh   = (_Float16*)alloc((size_t)2048 * 3072 * 2);
  _Float16* bWl   = (_Float16*)alloc((size_t)2048 * 3072 * 2);
  _Float16* w1h   = (_Float16*)alloc((size_t)128 * 18432 * 2);
  _Float16* w1l   = (_Float16*)alloc((size_t)128 * 18432 * 2);
  _Float16* Ahh   = (_Float16*)alloc((size_t)1664 * 3072 * 2);
  _Float16* All   = (_Float16*)alloc((size_t)1664 * 3072 * 2);
  _Float16* rawh  = (_Float16*)alloc((size_t)1664 * 2048 * 2);
  _Float16* rawl  = (_Float16*)alloc((size_t)1664 * 2048 * 2);
  float*    w2p   = (float*)   alloc((size_t)128 * 9 * 128 * 4);
  float*    w3p   = (float*)   alloc((size_t)128 * 9 * 128 * 4);
  // P (split-K=2 partials, 2x1664x2048 f32) aliases y1s (32x1568x128 f32):
  // lifetimes are stream-ordered disjoint.
  char*     big   = alloc((size_t)2 * PSLAB * 4);
  float*    Pbuf  = (float*)big;
  float*    y1s   = (float*)big;
  float*    y1v   = (float*)   alloc((size_t)1568 * 128 * 4);
  float*    y2v   = (float*)   alloc((size_t)392 * 128 * 4);
  float*    y3v   = (float*)   alloc((size_t)128 * 128 * 4);
  float*    sc    = (float*)   alloc((size_t)8 * 1614 * 4);
  int*      boxes = (int*)     alloc((size_t)8 * 4 * 4 * 4);
  float*    pfeat = (float*)   alloc((size_t)32 * 2048 * 4);
  float*    rfeat = (float*)   alloc((size_t)8 * 2048 * 4);

  prep_small<<<7 + 576 + 576, 256, 0, stream>>>(anch, areas, w2, w2p, w3, w3p);
  split_w<<<(2048 * 3072 / 8 + 255) / 256, 256, 0, stream>>>(bbw, bWh, bWl, 2048 * 3072 / 8);
  split_w1<<<(128 * 9 * 2048 + 255) / 256, 256, 0, stream>>>(w1, w1h, w1l);
  split_x<<<(1664 * 384 + 255) / 256, 256, 0, stream>>>(x, Ahh, All);

  gemm_bb_mfma<<<dim3(13, 16, 2), 256, 0, stream>>>(Ahh, All, bWh, bWl, Pbuf);
  bb_reduce_split<<<1664, 256, 0, stream>>>(Pbuf, bbb, rawh, rawl);
  feat_reduce<<<8 * 32, 256, 0, stream>>>(Pbuf, bbb, rfeat, 196);
  gemm_nav_mfma<<<dim3(13, 32), 256, 0, stream>>>(rawh, rawl, w1h, w1l, y1s);
  y1_reduce<<<(1568 * 128 + 255) / 256, 256, 0, stream>>>(y1s, b1, y1v);
  conv3x3s2<<<(8 * 7 * 7 * 128 + 255) / 256, 256, 0, stream>>>(y1v, w2p, b2, y2v, 14, 7);
  conv3x3s2<<<(8 * 4 * 4 * 128 + 255) / 256, 256, 0, stream>>>(y2v, w3p, b3, y3v, 7, 4);
  scores_kernel<<<(8 * 1614 + 255) / 256, 256, 0, stream>>>(
      y1v, y2v, y3v, t1w, t1b, t2w, t2b, t3w, t3b, sc);
  nms_kernel<<<8, 256, 0, stream>>>(sc, anch, areas, boxes);
  crop_kernel<<<(32 * 3 * 224 * 224) / 256, 256, 0, stream>>>(x, boxes, Ahh, All);
  gemm_bb_mfma<<<dim3(13, 16, 2), 256, 0, stream>>>(Ahh, All, bWh, bWl, Pbuf);
  feat_reduce<<<32 * 32, 256, 0, stream>>>(Pbuf, bbb, pfeat, 49);
  final_kernel<<<400, 256, 0, stream>>>(pfeat, rfeat, cw, cb, out);
}

// Round 11
// 371.755 us; speedup vs baseline: 2.4307x; 1.0032x over previous
//
#include <hip/hip_runtime.h>
#include <math.h>

// ---------------------------------------------------------------------------
// NTSNet forward. Big GEMMs on MFMA via 2-way f16 split (3 products: hh,hl,lh)
// R4: 2-phase dbuf + XCD swizzle (structural ceiling ~826 TF). R9: fused
// reduces, proven GEMM form. R10: n-fastest XCD pairing (A L2-reuse,
// FETCH 92->~55MB), coalesced split_w1 (LDS transpose), vectorized crop (h8),
// wave-shuffle NMS argmax, float4 y1_reduce.
// ---------------------------------------------------------------------------

typedef _Float16 h8 __attribute__((ext_vector_type(8)));
typedef float f32x4 __attribute__((ext_vector_type(4)));

#define ASCALE 256.0f
#define WSCALE 16384.0f
#define RSCALE (1.0f / (256.0f * 16384.0f))
#define PSLAB ((size_t)1664 * 2048)

__device__ __forceinline__ void gload16(const void* g, void* l) {
  __builtin_amdgcn_global_load_lds(
      (__attribute__((address_space(1))) void*)(void*)(uintptr_t)g,
      (__attribute__((address_space(3))) void*)l, 16, 0, 0);
}

// ---------------- merged small prep: anchors + w2/w3 permutes ---------------
__device__ void anchors_body(int i, int* anch, float* areas) {
  if (i >= 1614) return;
  int stride, oh, a, pos;
  double size, sc;
  const double C13 = 1.2599210498948732;
  const double C23 = 1.5874010519681994;
  if (i < 1176) {
    stride = 32; size = 48.0; oh = 14; a = i / 196; pos = i % 196;
    sc = (a / 3 == 0) ? C13 : C23;
  } else if (i < 1470) {
    int r = i - 1176; stride = 64; size = 96.0; oh = 7; a = r / 49; pos = r % 49;
    sc = (a / 3 == 0) ? C13 : C23;
  } else {
    int r = i - 1470; stride = 128; size = 192.0; oh = 4; a = r / 16; pos = r % 16;
    int si = a / 3;
    sc = (si == 0) ? 1.0 : ((si == 1) ? C13 : C23);
  }
  int ari = a % 3;
  double ar = (ari == 0) ? 0.667 : ((ari == 1) ? 1.0 : 1.5);
  int gy = pos / oh, gx = pos % oh;
  float cy = 0.5f * (float)stride + (float)(stride * gy);
  float cx = 0.5f * (float)stride + (float)(stride * gx);
  double ss = sqrt(ar);
  double hd = (size * sc) / ss;
  double wd = (size * sc) * ss;
  float hh = (float)(hd * 0.5), wh = (float)(wd * 0.5);
  int y0 = (int)((cy - hh) + 224.0f), x0 = (int)((cx - wh) + 224.0f);
  int y1i = (int)((cy + hh) + 224.0f), x1i = (int)((cx + wh) + 224.0f);
  anch[i * 4 + 0] = y0; anch[i * 4 + 1] = x0;
  anch[i * 4 + 2] = y1i; anch[i * 4 + 3] = x1i;
  areas[i] = (float)(y1i - y0) * (float)(x1i - x0);
}

__global__ __launch_bounds__(256) void prep_small(int* __restrict__ anch,
                                                  float* __restrict__ areas,
                                                  const float* __restrict__ w2,
                                                  float* __restrict__ w2p,
                                                  const float* __restrict__ w3,
                                                  float* __restrict__ w3p) {
  int b = blockIdx.x, t = threadIdx.x;
  if (b < 7) { anchors_body(b * 256 + t, anch, areas); return; }
  const float* src; float* dst; int idx;
  if (b < 7 + 576) { src = w2; dst = w2p; idx = (b - 7) * 256 + t; }
  else             { src = w3; dst = w3p; idx = (b - 583) * 256 + t; }
  if (idx >= 128 * 9 * 128) return;
  int c = idx % 128; int r2 = idx / 128; int tap = r2 % 9; int o = r2 / 9;
  dst[idx] = src[(o * 128 + c) * 9 + tap];
}

// ---------------- f32 -> f16 hi/lo split (linear, scale WSCALE) -------------
__global__ __launch_bounds__(256) void split_w(const float* __restrict__ src,
                                               _Float16* __restrict__ h,
                                               _Float16* __restrict__ l, int n8) {
  int i = blockIdx.x * 256 + threadIdx.x;
  if (i >= n8) return;
  float4 v0 = *(const float4*)(src + (size_t)i * 8);
  float4 v1 = *(const float4*)(src + (size_t)i * 8 + 4);
  float vv[8] = {v0.x, v0.y, v0.z, v0.w, v1.x, v1.y, v1.z, v1.w};
  h8 vh, vl;
#pragma unroll
  for (int j = 0; j < 8; ++j) {
    float s = vv[j] * WSCALE;
    _Float16 a = (_Float16)s;
    vh[j] = a; vl[j] = (_Float16)(s - (float)a);
  }
  *(h8*)(h + (size_t)i * 8) = vh;
  *(h8*)(l + (size_t)i * 8) = vl;
}

// ---------------- fused w1 permute + split (LDS transpose, both coalesced) --
// h/l[o][tap][c] = w1[o][c][tap]*WSCALE split. grid = 128 o x 4 c-tiles.
__global__ __launch_bounds__(256) void split_w1(const float* __restrict__ w1,
                                                _Float16* __restrict__ h,
                                                _Float16* __restrict__ l) {
  __shared__ float buf[4608];  // 512 c x 9 taps
  int o = blockIdx.x >> 2, ct = (blockIdx.x & 3) * 512;
  const float* src = w1 + (size_t)o * 18432 + (size_t)ct * 9;
  for (int i = threadIdx.x; i < 4608; i += 256) buf[i] = src[i];
  __syncthreads();
  for (int i = threadIdx.x; i < 4608; i += 256) {
    int tap = i / 512, c = i - tap * 512;
    float v = buf[c * 9 + tap] * WSCALE;
    _Float16 a = (_Float16)v;
    size_t o2 = ((size_t)o * 9 + tap) * 2048 + ct + c;
    h[o2] = a; l[o2] = (_Float16)(v - (float)a);
  }
}

// ---------------- x patchify -> A hi/lo [1664][3072] (scale ASCALE) ---------
__global__ __launch_bounds__(256) void split_x(const float* __restrict__ x,
                                               _Float16* __restrict__ Ah,
                                               _Float16* __restrict__ Al) {
  int i = blockIdx.x * 256 + threadIdx.x;
  if (i >= 1664 * 384) return;
  int kq = i % 384, m = i / 384;
  int k = kq * 8;
  h8 vh = {}, vl = {};
  if (m < 1568) {
    int b = m / 196, pos = m % 196;
    int c = k >> 10, r = (k >> 5) & 31, col = k & 31;
    int py = (pos / 14) * 32 + r, px = (pos % 14) * 32 + col;
    const float* sp2 = x + (((size_t)(b * 3 + c) * 448 + py) * 448 + px);
    float4 v0 = *(const float4*)sp2;
    float4 v1 = *(const float4*)(sp2 + 4);
    float vv[8] = {v0.x, v0.y, v0.z, v0.w, v1.x, v1.y, v1.z, v1.w};
#pragma unroll
    for (int j = 0; j < 8; ++j) {
      float s = vv[j] * ASCALE;
      _Float16 a = (_Float16)s;
      vh[j] = a; vl[j] = (_Float16)(s - (float)a);
    }
  }
  *(h8*)(Ah + (size_t)m * 3072 + k) = vh;
  *(h8*)(Al + (size_t)m * 3072 + k) = vl;
}

// ---------------- backbone GEMM (4-tensor LDS dbuf, split-K=2) --------------
// R10 swizzle: n-fastest pairing within XCD so each A m-tile's two n-users
// are adjacent blocks -> A fetched ~once from HBM (L2-served 2nd use).
__global__ __launch_bounds__(256) void gemm_bb_mfma(
    const _Float16* __restrict__ Ah, const _Float16* __restrict__ Al,
    const _Float16* __restrict__ Bh, const _Float16* __restrict__ Bl,
    float* __restrict__ P) {
  __shared__ __align__(16) char lds[65536];  // 2 x (Ah|Al|Bh|Bl tiles, 8KB each)
  const int t = threadIdx.x;
  // 208 xy-blocks = 8 XCD x 26; within XCD: m = r>>1 (13), n-parity = r&1.
  const int bid = blockIdx.x + 13 * blockIdx.y;
  const int r = bid >> 3;
  const int m0 = (r >> 1) * 128;
  const int n0 = ((bid & 7) * 2 + (r & 1)) * 128;
  const int kz = blockIdx.z;
  const int lane = t & 63, w = t >> 6;
  const int wm = (w >> 1) * 64, wn = (w & 1) * 64;
  const int lrow = lane & 15, kg = lane >> 4;

  int offA[4], offB[4];
#pragma unroll
  for (int i = 0; i < 4; ++i) {
    int ba = (wm + i * 16 + lrow) * 64 + kg * 16;
    offA[i] = ba ^ (((ba >> 7) & 3) << 4);
    int bb2 = (wn + i * 16 + lrow) * 64 + kg * 16;
    offB[i] = bb2 ^ (((bb2 >> 7) & 3) << 4);
  }
  size_t gAo[2], gBo[2];
  int ldso[2];
#pragma unroll
  for (int e = 0; e < 2; ++e) {
    int p = e * 256 + t;
    int lsl = p ^ ((p >> 3) & 3);   // inverse swizzle (involution) in slot units
    int row = lsl >> 2, kq = lsl & 3;
    gAo[e] = (size_t)(m0 + row) * 3072 + kq * 8;
    gBo[e] = (size_t)(n0 + row) * 3072 + kq * 8;
    ldso[e] = e * 4096 + (t & 192) * 16;
  }

  auto STAGE = [&](int buf, int k0) {
    char* L = lds + buf * 32768;
#pragma unroll
    for (int e = 0; e < 2; ++e) {
      gload16(Ah + gAo[e] + k0, L + ldso[e]);
      gload16(Al + gAo[e] + k0, L + 8192 + ldso[e]);
      gload16(Bh + gBo[e] + k0, L + 16384 + ldso[e]);
      gload16(Bl + gBo[e] + k0, L + 24576 + ldso[e]);
    }
  };

  f32x4 acc[4][4] = {};
  const int kbeg = kz * 1536, kend = kbeg + 1536;
  STAGE(0, kbeg);
  __syncthreads();
  int cur = 0;
  for (int k0 = kbeg; k0 < kend; k0 += 32) {
    if (k0 + 32 < kend) STAGE(cur ^ 1, k0 + 32);  // issue-early: hides under MFMA
    const char* L = lds + cur * 32768;
    h8 fah[4], fal[4], fbh[4], fbl[4];
#pragma unroll
    for (int i = 0; i < 4; ++i) {
      fah[i] = *(const h8*)(L + offA[i]);
      fal[i] = *(const h8*)(L + 8192 + offA[i]);
      fbh[i] = *(const h8*)(L + 16384 + offB[i]);
      fbl[i] = *(const h8*)(L + 24576 + offB[i]);
    }
#pragma unroll
    for (int i = 0; i < 4; ++i)
#pragma unroll
      for (int j = 0; j < 4; ++j)
        acc[i][j] = __builtin_amdgcn_mfma_f32_16x16x32_f16(fah[i], fbh[j], acc[i][j], 0, 0, 0);
#pragma unroll
    for (int i = 0; i < 4; ++i)
#pragma unroll
      for (int j = 0; j < 4; ++j)
        acc[i][j] = __builtin_amdgcn_mfma_f32_16x16x32_f16(fah[i], fbl[j], acc[i][j], 0, 0, 0);
#pragma unroll
    for (int i = 0; i < 4; ++i)
#pragma unroll
      for (int j = 0; j < 4; ++j)
        acc[i][j] = __builtin_amdgcn_mfma_f32_16x16x32_f16(fal[i], fbh[j], acc[i][j], 0, 0, 0);
    __syncthreads();
    cur ^= 1;
  }
  float* Pz = P + (size_t)kz * PSLAB;
  const int prow = (lane >> 4) * 4;
#pragma unroll
  for (int i = 0; i < 4; ++i) {
#pragma unroll
    for (int j = 0; j < 4; ++j) {
      int n = n0 + wn + j * 16 + lrow;
#pragma unroll
      for (int r2 = 0; r2 < 4; ++r2) {
        int m = m0 + wm + i * 16 + prow + r2;
        Pz[(size_t)m * 2048 + n] = acc[i][j][r2];
      }
    }
  }
}

// ---------------- split-K reduce -> f16 hi/lo split only (for nav input) ----
__global__ __launch_bounds__(256) void bb_reduce_split(const float* __restrict__ P,
                                                       const float* __restrict__ bias,
                                                       _Float16* __restrict__ h,
                                                       _Float16* __restrict__ l) {
  int idx = blockIdx.x * 256 + threadIdx.x;
  int m = idx >> 8, col = (idx & 255) * 8;
  if (m >= 1664) return;
  size_t o = (size_t)m * 2048 + col;
  if (m >= 1568) {
    h8 z = {};
    *(h8*)(h + o) = z;
    *(h8*)(l + o) = z;
    return;
  }
  h8 vh, vl;
#pragma unroll
  for (int q = 0; q < 2; ++q) {
    float4 s0 = *(const float4*)(P + o + q * 4);
    float4 s1 = *(const float4*)(P + PSLAB + o + q * 4);
    float4 b = *(const float4*)(bias + col + q * 4);
    float v[4];
    v[0] = fmaxf(fmaf(s0.x + s1.x, RSCALE, b.x), 0.f);
    v[1] = fmaxf(fmaf(s0.y + s1.y, RSCALE, b.y), 0.f);
    v[2] = fmaxf(fmaf(s0.z + s1.z, RSCALE, b.z), 0.f);
    v[3] = fmaxf(fmaf(s0.w + s1.w, RSCALE, b.w), 0.f);
#pragma unroll
    for (int j = 0; j < 4; ++j) {
      float s = v[j] * ASCALE;
      _Float16 a = (_Float16)s;
      vh[q * 4 + j] = a; vl[q * 4 + j] = (_Float16)(s - (float)a);
    }
  }
  *(h8*)(h + o) = vh;
  *(h8*)(l + o) = vl;
}

// ---------------- fused split-K reduce + relu + spatial mean ----------------
__global__ __launch_bounds__(256) void feat_reduce(const float* __restrict__ P,
                                                   const float* __restrict__ bias,
                                                   float* __restrict__ out,
                                                   int rows) {
  int g = blockIdx.x >> 5, chunk = blockIdx.x & 31;
  int col = chunk * 64 + (threadIdx.x & 63), rl = threadIdx.x >> 6;
  const float* base0 = P + ((size_t)g * rows) * 2048 + col;
  const float* base1 = base0 + PSLAB;
  float bcol = bias[col];
  float s = 0.f;
  for (int r = rl; r < rows; r += 4)
    s += fmaxf(fmaf(base0[(size_t)r * 2048] + base1[(size_t)r * 2048], RSCALE, bcol), 0.f);
  __shared__ float red[4][64];
  red[rl][threadIdx.x & 63] = s;
  __syncthreads();
  if (rl == 0) {
    int c = threadIdx.x & 63;
    out[(size_t)g * 2048 + col] =
        ((red[0][c] + red[1][c]) + (red[2][c] + red[3][c])) / (float)rows;
  }
}

// ---------------- navigator y1 GEMM (split-K=32, 4-tensor dbuf) -------------
__global__ __launch_bounds__(256) void gemm_nav_mfma(
    const _Float16* __restrict__ Ah, const _Float16* __restrict__ Al,
    const _Float16* __restrict__ Bh, const _Float16* __restrict__ Bl,
    float* __restrict__ part) {
  __shared__ __align__(16) char lds[65536];
  const int t = threadIdx.x;
  // XCD-chunked bijective swizzle: 416 blocks = 8 XCD x 52 (m fastest per sp).
  const int bid = blockIdx.x + 13 * blockIdx.y;
  const int orig = (bid & 7) * 52 + (bid >> 3);
  const int m0 = (orig % 13) * 128;
  const int sp = orig / 13;  // 0..31
  const int lane = t & 63, w = t >> 6;
  const int wm = (w >> 1) * 64, wn = (w & 1) * 64;
  const int lrow = lane & 15, kg = lane >> 4;

  int offA[4], offB[4];
#pragma unroll
  for (int i = 0; i < 4; ++i) {
    int ba = (wm + i * 16 + lrow) * 64 + kg * 16;
    offA[i] = ba ^ (((ba >> 7) & 3) << 4);
    int bb2 = (wn + i * 16 + lrow) * 64 + kg * 16;
    offB[i] = bb2 ^ (((bb2 >> 7) & 3) << 4);
  }
  size_t gBo[2];
  int ldso[2], akq8[2], ab[2], apy[2], apx[2], amv[2];
#pragma unroll
  for (int e = 0; e < 2; ++e) {
    int p = e * 256 + t;
    int lsl = p ^ ((p >> 3) & 3);
    int row = lsl >> 2, kq = lsl & 3;
    gBo[e] = (size_t)row * 18432 + kq * 8;
    ldso[e] = e * 4096 + (t & 192) * 16;
    int m = m0 + row;
    amv[e] = (m < 1568);
    int b = m / 196, pos = m % 196;
    ab[e] = b; apy[e] = pos / 14; apx[e] = pos % 14;
    akq8[e] = kq * 8;
  }

  auto STAGE = [&](int buf, int k0) {
    const int tap = k0 >> 11;   // 32 | 2048: no tap straddle within a K-step
    const int c = k0 & 2047;
    const int dy = tap / 3 - 1, dx = tap % 3 - 1;
    char* L = lds + buf * 32768;
#pragma unroll
    for (int e = 0; e < 2; ++e) {
      int sy = apy[e] + dy, sx = apx[e] + dx;
      bool ok = amv[e] && ((unsigned)sy < 14u) && ((unsigned)sx < 14u);
      size_t rowi = ok ? (size_t)(ab[e] * 196 + sy * 14 + sx) : (size_t)1600;
      size_t ao = rowi * 2048 + c + akq8[e];
      gload16(Ah + ao, L + ldso[e]);
      gload16(Al + ao, L + 8192 + ldso[e]);
      gload16(Bh + gBo[e] + k0, L + 16384 + ldso[e]);
      gload16(Bl + gBo[e] + k0, L + 24576 + ldso[e]);
    }
  };

  f32x4 acc[4][4] = {};
  const int kbeg = sp * 576, kend = kbeg + 576;
  STAGE(0, kbeg);
  __syncthreads();
  int cur = 0;
  for (int k0 = kbeg; k0 < kend; k0 += 32) {
    if (k0 + 32 < kend) STAGE(cur ^ 1, k0 + 32);
    const char* L = lds + cur * 32768;
    h8 fah[4], fal[4], fbh[4], fbl[4];
#pragma unroll
    for (int i = 0; i < 4; ++i) {
      fah[i] = *(const h8*)(L + offA[i]);
      fal[i] = *(const h8*)(L + 8192 + offA[i]);
      fbh[i] = *(const h8*)(L + 16384 + offB[i]);
      fbl[i] = *(const h8*)(L + 24576 + offB[i]);
    }
#pragma unroll
    for (int i = 0; i < 4; ++i)
#pragma unroll
      for (int j = 0; j < 4; ++j)
        acc[i][j] = __builtin_amdgcn_mfma_f32_16x16x32_f16(fah[i], fbh[j], acc[i][j], 0, 0, 0);
#pragma unroll
    for (int i = 0; i < 4; ++i)
#pragma unroll
      for (int j = 0; j < 4; ++j)
        acc[i][j] = __builtin_amdgcn_mfma_f32_16x16x32_f16(fah[i], fbl[j], acc[i][j], 0, 0, 0);
#pragma unroll
    for (int i = 0; i < 4; ++i)
#pragma unroll
      for (int j = 0; j < 4; ++j)
        acc[i][j] = __builtin_amdgcn_mfma_f32_16x16x32_f16(fal[i], fbh[j], acc[i][j], 0, 0, 0);
    __syncthreads();
    cur ^= 1;
  }
  const int prow = (lane >> 4) * 4;
#pragma unroll
  for (int i = 0; i < 4; ++i) {
#pragma unroll
    for (int j = 0; j < 4; ++j) {
      int n = wn + j * 16 + lrow;
#pragma unroll
      for (int r = 0; r < 4; ++r) {
        int m = m0 + wm + i * 16 + prow + r;
        if (m < 1568)
          part[((size_t)sp * 1568 + m) * 128 + n] = acc[i][j][r] * RSCALE;
      }
    }
  }
}

__global__ __launch_bounds__(256) void y1_reduce(const float* __restrict__ part,
                                                 const float* __restrict__ b1,
                                                 float* __restrict__ y1) {
  int idx = blockIdx.x * 256 + threadIdx.x;   // over (1568*128)/4
  if (idx >= 1568 * 32) return;
  int o = (idx * 4) & 127;
  float4 s = *(const float4*)(b1 + o);
#pragma unroll
  for (int sp = 0; sp < 32; ++sp) {
    float4 v = *(const float4*)(part + (size_t)sp * 1568 * 128 + (size_t)idx * 4);
    s.x += v.x; s.y += v.y; s.z += v.z; s.w += v.w;
  }
  s.x = fmaxf(s.x, 0.f); s.y = fmaxf(s.y, 0.f);
  s.z = fmaxf(s.z, 0.f); s.w = fmaxf(s.w, 0.f);
  *(float4*)(y1 + (size_t)idx * 4) = s;
}

// ---------------- small 3x3 stride-2 pad-1 convs (128->128 ch, NHWC) --------
__global__ __launch_bounds__(256) void conv3x3s2(const float* __restrict__ in,
                                                 const float* __restrict__ wp,
                                                 const float* __restrict__ bias,
                                                 float* __restrict__ out,
                                                 int Hin, int Hout) {
  int idx = blockIdx.x * 256 + threadIdx.x;
  int total = 8 * Hout * Hout * 128;
  if (idx >= total) return;
  int o = idx & 127; int pos = idx >> 7;
  int ox = pos % Hout; int t2 = pos / Hout; int oy = t2 % Hout; int b = t2 / Hout;
  float acc = bias[o];
  for (int dy = 0; dy < 3; ++dy) {
    int iy = 2 * oy - 1 + dy;
    if (iy < 0 || iy >= Hin) continue;
    for (int dx = 0; dx < 3; ++dx) {
      int ix = 2 * ox - 1 + dx;
      if (ix < 0 || ix >= Hin) continue;
      const float* ip = in + ((b * Hin + iy) * Hin + ix) * 128;
      const float* wgt = wp + (o * 9 + dy * 3 + dx) * 128;
#pragma unroll 4
      for (int c = 0; c < 128; c += 4) {
        float4 a = *(const float4*)(ip + c);
        float4 ww = *(const float4*)(wgt + c);
        acc += a.x * ww.x + a.y * ww.y + a.z * ww.z + a.w * ww.w;
      }
    }
  }
  out[idx] = fmaxf(acc, 0.f);
}

// ---------------- rpn scores ------------------------------------------------
__global__ __launch_bounds__(256) void scores_kernel(
    const float* __restrict__ y1, const float* __restrict__ y2,
    const float* __restrict__ y3, const float* __restrict__ t1w,
    const float* __restrict__ t1b, const float* __restrict__ t2w,
    const float* __restrict__ t2b, const float* __restrict__ t3w,
    const float* __restrict__ t3b, float* __restrict__ scores) {
  int idx = blockIdx.x * 256 + threadIdx.x;
  if (idx >= 8 * 1614) return;
  int b = idx / 1614, sI = idx % 1614;
  const float* f; const float* w; float bias;
  if (sI < 1176) {
    int a = sI / 196;
    f = y1 + (b * 196 + (sI % 196)) * 128; w = t1w + a * 128; bias = t1b[a];
  } else if (sI < 1470) {
    int r = sI - 1176; int a = r / 49;
    f = y2 + (b * 49 + (r % 49)) * 128; w = t2w + a * 128; bias = t2b[a];
  } else {
    int r = sI - 1470; int a = r / 16;
    f = y3 + (b * 16 + (r % 16)) * 128; w = t3w + a * 128; bias = t3b[a];
  }
  float acc = 0.f;
  for (int c = 0; c < 128; c += 4) {
    float4 a4 = *(const float4*)(f + c);
    float4 w4 = *(const float4*)(w + c);
    acc += a4.x * w4.x + a4.y * w4.y + a4.z * w4.z + a4.w * w4.w;
  }
  scores[idx] = acc + bias;
}

// ---------------- greedy NMS (per batch block, wave-shuffle argmax) ---------
__global__ __launch_bounds__(256) void nms_kernel(const float* __restrict__ scores,
                                                  const int* __restrict__ anch,
                                                  const float* __restrict__ areas,
                                                  int* __restrict__ boxes) {
  const int b = blockIdx.x, t = threadIdx.x;
  const int lane = t & 63, wid = t >> 6;
  const float* s = scores + b * 1614;
  __shared__ unsigned char valid[1614];
  __shared__ float wv[4];
  __shared__ int wi[4];
  __shared__ int ssel;
  for (int i = t; i < 1614; i += 256) valid[i] = 1;
  __syncthreads();
  for (int n = 0; n < 4; ++n) {
    float best = -INFINITY; int bi = 0x7fffffff;
    for (int i = t; i < 1614; i += 256) {
      if (valid[i]) {
        float v = s[i];
        if (v > best || (v == best && i < bi)) { best = v; bi = i; }
      }
    }
#pragma unroll
    for (int off = 32; off > 0; off >>= 1) {
      float ov = __shfl_down(best, off, 64);
      int oi = __shfl_down(bi, off, 64);
      if (ov > best || (ov == best && oi < bi)) { best = ov; bi = oi; }
    }
    if (lane == 0) { wv[wid] = best; wi[wid] = bi; }
    __syncthreads();
    if (t == 0) {
      float bv = wv[0]; int bj = wi[0];
#pragma unroll
      for (int q = 1; q < 4; ++q)
        if (wv[q] > bv || (wv[q] == bv && wi[q] < bj)) { bv = wv[q]; bj = wi[q]; }
      if (bj > 1613) bj = 0;  // all-suppressed fallback
      ssel = bj;
      ((int4*)boxes)[b * 4 + n] = ((const int4*)anch)[bj];
    }
    __syncthreads();
    int sel = ssel;
    const int4 bb = ((const int4*)anch)[sel];
    const float Ai = areas[sel];
    for (int i = t; i < 1614; i += 256) {
      if (!valid[i]) continue;
      const int4 ab = ((const int4*)anch)[i];
      float sy = fmaxf((float)ab.x, (float)bb.x);
      float sx = fmaxf((float)ab.y, (float)bb.y);
      float ey = fminf((float)ab.z, (float)bb.z);
      float ex = fminf((float)ab.w, (float)bb.w);
      float ly = ey - sy, lx = ex - sx;
      float inter = (ly < 0.f || lx < 0.f) ? 0.f : ly * lx;
      float iou = inter / (areas[i] + Ai - inter);
      if (iou >= 0.25f) valid[i] = 0;
    }
    __syncthreads();
  }
}

// ---------------- bilinear crop -> A hi/lo (8-px vectorized, h8 writes) -----
__global__ __launch_bounds__(256) void crop_kernel(const float* __restrict__ x,
                                                   const int* __restrict__ boxes,
                                                   _Float16* __restrict__ Ah,
                                                   _Float16* __restrict__ Al) {
  int idx = blockIdx.x * 256 + threadIdx.x;   // over 32*3*224*28
  if (idx >= 32 * 3 * 224 * 28) return;
  int pxq = idx % 28; int t1 = idx / 28; int py = t1 % 224; int t2 = t1 / 224;
  int c = t2 % 3; int p = t2 / 3;
  int b = p >> 2;
  int px0 = pxq * 8;
  const int4 bb = ((const int4*)boxes)[p];
  float ty = (float)py / 223.0f;
  float ys = (float)bb.x + ty * (float)(bb.z - bb.x - 1);
  float yf = floorf(ys);
  float wy = ys - yf;
  int yl = (int)yf;
  int yh = min(yl + 1, 895);
  const float* img = x + (size_t)(b * 3 + c) * 448 * 448;
  auto samp = [&](int yy, int xx) -> float {
    yy -= 224; xx -= 224;
    if (yy < 0 || yy >= 448 || xx < 0 || xx >= 448) return 0.f;
    return img[yy * 448 + xx];
  };
  h8 vh, vl;
#pragma unroll
  for (int q = 0; q < 8; ++q) {
    int px = px0 + q;
    float txf = (float)px / 223.0f;
    float xs = (float)bb.y + txf * (float)(bb.w - bb.y - 1);
    float xf = floorf(xs);
    float wx = xs - xf;
    int xl = (int)xf;
    int xh = min(xl + 1, 895);
    float v00 = samp(yl, xl), v01 = samp(yl, xh);
    float v10 = samp(yh, xl), v11 = samp(yh, xh);
    float top = v00 * (1.f - wx) + v01 * wx;
    float bot = v10 * (1.f - wx) + v11 * wx;
    float val = top * (1.f - wy) + bot * wy;
    float sv = val * ASCALE;
    _Float16 a = (_Float16)sv;
    vh[q] = a; vl[q] = (_Float16)(sv - (float)a);
  }
  int i = py >> 5, r = py & 31, j = px0 >> 5, col = px0 & 31;
  int m = p * 49 + i * 7 + j;
  int k = (c << 10) + (r << 5) + col;
  *(h8*)(Ah + (size_t)m * 3072 + k) = vh;
  *(h8*)(Al + (size_t)m * 3072 + k) = vl;
}

// ---------------- final linear: one wave per (b, class) ---------------------
__global__ __launch_bounds__(256) void final_kernel(const float* __restrict__ pfeat,
                                                    const float* __restrict__ rfeat,
                                                    const float* __restrict__ cw,
                                                    const float* __restrict__ cb,
                                                    float* __restrict__ out) {
  int gw = (blockIdx.x * 256 + threadIdx.x) >> 6;
  int lane = threadIdx.x & 63;
  if (gw >= 1600) return;
  int b = gw / 200, j = gw % 200;
  const float* wr = cw + (size_t)j * 10240;
  const float* pf = pfeat + (size_t)b * 8192;
  float acc = 0.f;
  for (int k = lane * 4; k < 8192; k += 256) {
    float4 a = *(const float4*)(pf + k);
    float4 w = *(const float4*)(wr + k);
    acc += a.x * w.x + a.y * w.y + a.z * w.z + a.w * w.w;
  }
  const float* rf = rfeat + (size_t)b * 2048;
  const float* wr2 = wr + 8192;
  for (int k = lane * 4; k < 2048; k += 256) {
    float4 a = *(const float4*)(rf + k);
    float4 w = *(const float4*)(wr2 + k);
    acc += a.x * w.x + a.y * w.y + a.z * w.z + a.w * w.w;
  }
#pragma unroll
  for (int off = 32; off > 0; off >>= 1) acc += __shfl_down(acc, off, 64);
  if (lane == 0) out[b * 200 + j] = acc + cb[j];
}

// ---------------------------------------------------------------------------
extern "C" void kernel_launch(void* const* d_in, const int* in_sizes, int n_in,
                              void* d_out, int out_size, void* d_ws, size_t ws_size,
                              hipStream_t stream) {
  const float* x   = (const float*)d_in[0];
  const float* bbw = (const float*)d_in[1];
  const float* bbb = (const float*)d_in[2];
  const float* w1  = (const float*)d_in[3];
  const float* b1  = (const float*)d_in[4];
  const float* t1w = (const float*)d_in[5];
  const float* t1b = (const float*)d_in[6];
  const float* w2  = (const float*)d_in[7];
  const float* b2  = (const float*)d_in[8];
  const float* t2w = (const float*)d_in[9];
  const float* t2b = (const float*)d_in[10];
  const float* w3  = (const float*)d_in[11];
  const float* b3  = (const float*)d_in[12];
  const float* t3w = (const float*)d_in[13];
  const float* t3b = (const float*)d_in[14];
  const float* cw  = (const float*)d_in[15];
  const float* cb  = (const float*)d_in[16];
  float* out = (float*)d_out;

  char* p = (char*)d_ws;
  auto alloc = [&](size_t bytes) -> char* {
    char* r = p; p += (bytes + 255) & ~(size_t)255; return r;
  };
  int*      anch  = (int*)     alloc((size_t)1614 * 4 * 4);
  float*    areas = (float*)   alloc((size_t)1614 * 4);
  _Float16* bWh   = (_Float16*)alloc((size_t)2048 * 3072 * 2);
  _Float16* bWl   = (_Float16*)alloc((size_t)2048 * 3072 * 2);
  _Float16* w1h   = (_Float16*)alloc((size_t)128 * 18432 * 2);
  _Float16* w1l   = (_Float16*)alloc((size_t)128 * 18432 * 2);
  _Float16* Ahh   = (_Float16*)alloc((size_t)1664 * 3072 * 2);
  _Float16* All   = (_Float16*)alloc((size_t)1664 * 3072 * 2);
  _Float16* rawh  = (_Float16*)alloc((size_t)1664 * 2048 * 2);
  _Float16* rawl  = (_Float16*)alloc((size_t)1664 * 2048 * 2);
  float*    w2p   = (float*)   alloc((size_t)128 * 9 * 128 * 4);
  float*    w3p   = (float*)   alloc((size_t)128 * 9 * 128 * 4);
  // P (split-K=2 partials) aliases y1s (32x1568x128 f32): disjoint lifetimes.
  char*     big   = alloc((size_t)2 * PSLAB * 4);
  float*    Pbuf  = (float*)big;
  float*    y1s   = (float*)big;
  float*    y1v   = (float*)   alloc((size_t)1568 * 128 * 4);
  float*    y2v   = (float*)   alloc((size_t)392 * 128 * 4);
  float*    y3v   = (float*)   alloc((size_t)128 * 128 * 4);
  float*    sc    = (float*)   alloc((size_t)8 * 1614 * 4);
  int*      boxes = (int*)     alloc((size_t)8 * 4 * 4 * 4);
  float*    pfeat = (float*)   alloc((size_t)32 * 2048 * 4);
  float*    rfeat = (float*)   alloc((size_t)8 * 2048 * 4);

  prep_small<<<7 + 576 + 576, 256, 0, stream>>>(anch, areas, w2, w2p, w3, w3p);
  split_w<<<(2048 * 3072 / 8 + 255) / 256, 256, 0, stream>>>(bbw, bWh, bWl, 2048 * 3072 / 8);
  split_w1<<<512, 256, 0, stream>>>(w1, w1h, w1l);
  split_x<<<(1664 * 384 + 255) / 256, 256, 0, stream>>>(x, Ahh, All);

  gemm_bb_mfma<<<dim3(13, 16, 2), 256, 0, stream>>>(Ahh, All, bWh, bWl, Pbuf);
  bb_reduce_split<<<1664, 256, 0, stream>>>(Pbuf, bbb, rawh, rawl);
  feat_reduce<<<8 * 32, 256, 0, stream>>>(Pbuf, bbb, rfeat, 196);
  gemm_nav_mfma<<<dim3(13, 32), 256, 0, stream>>>(rawh, rawl, w1h, w1l, y1s);
  y1_reduce<<<(1568 * 32 + 255) / 256, 256, 0, stream>>>(y1s, b1, y1v);
  conv3x3s2<<<(8 * 7 * 7 * 128 + 255) / 256, 256, 0, stream>>>(y1v, w2p, b2, y2v, 14, 7);
  conv3x3s2<<<(8 * 4 * 4 * 128 + 255) / 256, 256, 0, stream>>>(y2v, w3p, b3, y3v, 7, 4);
  scores_kernel<<<(8 * 1614 + 255) / 256, 256, 0, stream>>>(
      y1v, y2v, y3v, t1w, t1b, t2w, t2b, t3w, t3b, sc);
  nms_kernel<<<8, 256, 0, stream>>>(sc, anch, areas, boxes);
  crop_kernel<<<(32 * 3 * 224 * 28 + 255) / 256, 256, 0, stream>>>(x, boxes, Ahh, All);
  gemm_bb_mfma<<<dim3(13, 16, 2), 256, 0, stream>>>(Ahh, All, bWh, bWl, Pbuf);
  feat_reduce<<<32 * 32, 256, 0, stream>>>(Pbuf, bbb, pfeat, 49);
  final_kernel<<<400, 256, 0, stream>>>(pfeat, rfeat, cw, cb, out);
}

// Round 12
// 362.400 us; speedup vs baseline: 2.4934x; 1.0258x over previous
//
#include <hip/hip_runtime.h>
#include <math.h>

// ---------------------------------------------------------------------------
// NTSNet forward. Big GEMMs on MFMA via 2-way f16 split (3 products: hh,hl,lh)
// R4: 2-phase dbuf + XCD swizzle (bb GEMM at its ~776TF structural plateau --
// leave K-loop alone; R6-R8 all regressed). R9/R10: fused reduces, vectorized
// tail. R11: nav 64-row tiles + split-K=16 (48KB LDS, half partial traffic),
// nav_prep fusion (single P read -> rawh/rawl + rfeat), mega_prep (1 launch).
// ---------------------------------------------------------------------------

typedef _Float16 h8 __attribute__((ext_vector_type(8)));
typedef float f32x4 __attribute__((ext_vector_type(4)));

#define ASCALE 256.0f
#define WSCALE 16384.0f
#define RSCALE (1.0f / (256.0f * 16384.0f))
#define PSLAB ((size_t)1664 * 2048)

__device__ __forceinline__ void gload16(const void* g, void* l) {
  __builtin_amdgcn_global_load_lds(
      (__attribute__((address_space(1))) void*)(void*)(uintptr_t)g,
      (__attribute__((address_space(3))) void*)l, 16, 0, 0);
}

// ---------------- anchors ----------------------------------------------------
__device__ void anchors_body(int i, int* anch, float* areas) {
  if (i >= 1614) return;
  int stride, oh, a, pos;
  double size, sc;
  const double C13 = 1.2599210498948732;
  const double C23 = 1.5874010519681994;
  if (i < 1176) {
    stride = 32; size = 48.0; oh = 14; a = i / 196; pos = i % 196;
    sc = (a / 3 == 0) ? C13 : C23;
  } else if (i < 1470) {
    int r = i - 1176; stride = 64; size = 96.0; oh = 7; a = r / 49; pos = r % 49;
    sc = (a / 3 == 0) ? C13 : C23;
  } else {
    int r = i - 1470; stride = 128; size = 192.0; oh = 4; a = r / 16; pos = r % 16;
    int si = a / 3;
    sc = (si == 0) ? 1.0 : ((si == 1) ? C13 : C23);
  }
  int ari = a % 3;
  double ar = (ari == 0) ? 0.667 : ((ari == 1) ? 1.0 : 1.5);
  int gy = pos / oh, gx = pos % oh;
  float cy = 0.5f * (float)stride + (float)(stride * gy);
  float cx = 0.5f * (float)stride + (float)(stride * gx);
  double ss = sqrt(ar);
  double hd = (size * sc) / ss;
  double wd = (size * sc) * ss;
  float hh = (float)(hd * 0.5), wh = (float)(wd * 0.5);
  int y0 = (int)((cy - hh) + 224.0f), x0 = (int)((cx - wh) + 224.0f);
  int y1i = (int)((cy + hh) + 224.0f), x1i = (int)((cx + wh) + 224.0f);
  anch[i * 4 + 0] = y0; anch[i * 4 + 1] = x0;
  anch[i * 4 + 2] = y1i; anch[i * 4 + 3] = x1i;
  areas[i] = (float)(y1i - y0) * (float)(x1i - x0);
}

// ---------------- mega prep: anchors | w2p | w3p | split bbw | split w1 | split x
// block ranges: [0,7) [7,583) [583,1159) [1159,4231) [4231,4743) [4743,7239)
__global__ __launch_bounds__(256) void mega_prep(
    int* __restrict__ anch, float* __restrict__ areas,
    const float* __restrict__ w2, float* __restrict__ w2p,
    const float* __restrict__ w3, float* __restrict__ w3p,
    const float* __restrict__ bbw, _Float16* __restrict__ bWh, _Float16* __restrict__ bWl,
    const float* __restrict__ w1, _Float16* __restrict__ w1h, _Float16* __restrict__ w1l,
    const float* __restrict__ x, _Float16* __restrict__ Ah, _Float16* __restrict__ Al) {
  __shared__ float buf[4608];
  int b = blockIdx.x, t = threadIdx.x;
  if (b < 7) { anchors_body(b * 256 + t, anch, areas); return; }
  if (b < 1159) {  // w2/w3 permutes
    const float* src; float* dst; int idx;
    if (b < 583) { src = w2; dst = w2p; idx = (b - 7) * 256 + t; }
    else         { src = w3; dst = w3p; idx = (b - 583) * 256 + t; }
    if (idx >= 128 * 9 * 128) return;
    int c = idx % 128; int r2 = idx / 128; int tap = r2 % 9; int o = r2 / 9;
    dst[idx] = src[(o * 128 + c) * 9 + tap];
    return;
  }
  if (b < 4231) {  // split bbw (linear)
    int i = (b - 1159) * 256 + t;
    float4 v0 = *(const float4*)(bbw + (size_t)i * 8);
    float4 v1 = *(const float4*)(bbw + (size_t)i * 8 + 4);
    float vv[8] = {v0.x, v0.y, v0.z, v0.w, v1.x, v1.y, v1.z, v1.w};
    h8 vh, vl;
#pragma unroll
    for (int j = 0; j < 8; ++j) {
      float s = vv[j] * WSCALE;
      _Float16 a = (_Float16)s;
      vh[j] = a; vl[j] = (_Float16)(s - (float)a);
    }
    *(h8*)(bWh + (size_t)i * 8) = vh;
    *(h8*)(bWl + (size_t)i * 8) = vl;
    return;
  }
  if (b < 4743) {  // w1 permute+split via LDS transpose
    int bb = b - 4231;
    int o = bb >> 2, ct = (bb & 3) * 512;
    const float* src = w1 + (size_t)o * 18432 + (size_t)ct * 9;
    for (int i = t; i < 4608; i += 256) buf[i] = src[i];
    __syncthreads();
    for (int i = t; i < 4608; i += 256) {
      int tap = i / 512, c = i - tap * 512;
      float v = buf[c * 9 + tap] * WSCALE;
      _Float16 a = (_Float16)v;
      size_t o2 = ((size_t)o * 9 + tap) * 2048 + ct + c;
      w1h[o2] = a; w1l[o2] = (_Float16)(v - (float)a);
    }
    return;
  }
  {  // split x patchify
    int i = (b - 4743) * 256 + t;
    int kq = i % 384, m = i / 384;
    int k = kq * 8;
    h8 vh = {}, vl = {};
    if (m < 1568) {
      int bb = m / 196, pos = m % 196;
      int c = k >> 10, r = (k >> 5) & 31, col = k & 31;
      int py = (pos / 14) * 32 + r, px = (pos % 14) * 32 + col;
      const float* sp2 = x + (((size_t)(bb * 3 + c) * 448 + py) * 448 + px);
      float4 v0 = *(const float4*)sp2;
      float4 v1 = *(const float4*)(sp2 + 4);
      float vv[8] = {v0.x, v0.y, v0.z, v0.w, v1.x, v1.y, v1.z, v1.w};
#pragma unroll
      for (int j = 0; j < 8; ++j) {
        float s = vv[j] * ASCALE;
        _Float16 a = (_Float16)s;
        vh[j] = a; vl[j] = (_Float16)(s - (float)a);
      }
    }
    *(h8*)(Ah + (size_t)m * 3072 + k) = vh;
    *(h8*)(Al + (size_t)m * 3072 + k) = vl;
  }
}

// ---------------- backbone GEMM (4-tensor LDS dbuf, split-K=2) --------------
__global__ __launch_bounds__(256) void gemm_bb_mfma(
    const _Float16* __restrict__ Ah, const _Float16* __restrict__ Al,
    const _Float16* __restrict__ Bh, const _Float16* __restrict__ Bl,
    float* __restrict__ P) {
  __shared__ __align__(16) char lds[65536];  // 2 x (Ah|Al|Bh|Bl tiles, 8KB each)
  const int t = threadIdx.x;
  const int bid = blockIdx.x + 13 * blockIdx.y;
  const int r = bid >> 3;
  const int m0 = (r >> 1) * 128;
  const int n0 = ((bid & 7) * 2 + (r & 1)) * 128;
  const int kz = blockIdx.z;
  const int lane = t & 63, w = t >> 6;
  const int wm = (w >> 1) * 64, wn = (w & 1) * 64;
  const int lrow = lane & 15, kg = lane >> 4;

  int offA[4], offB[4];
#pragma unroll
  for (int i = 0; i < 4; ++i) {
    int ba = (wm + i * 16 + lrow) * 64 + kg * 16;
    offA[i] = ba ^ (((ba >> 7) & 3) << 4);
    int bb2 = (wn + i * 16 + lrow) * 64 + kg * 16;
    offB[i] = bb2 ^ (((bb2 >> 7) & 3) << 4);
  }
  size_t gAo[2], gBo[2];
  int ldso[2];
#pragma unroll
  for (int e = 0; e < 2; ++e) {
    int p = e * 256 + t;
    int lsl = p ^ ((p >> 3) & 3);   // inverse swizzle (involution) in slot units
    int row = lsl >> 2, kq = lsl & 3;
    gAo[e] = (size_t)(m0 + row) * 3072 + kq * 8;
    gBo[e] = (size_t)(n0 + row) * 3072 + kq * 8;
    ldso[e] = e * 4096 + (t & 192) * 16;
  }

  auto STAGE = [&](int buf, int k0) {
    char* L = lds + buf * 32768;
#pragma unroll
    for (int e = 0; e < 2; ++e) {
      gload16(Ah + gAo[e] + k0, L + ldso[e]);
      gload16(Al + gAo[e] + k0, L + 8192 + ldso[e]);
      gload16(Bh + gBo[e] + k0, L + 16384 + ldso[e]);
      gload16(Bl + gBo[e] + k0, L + 24576 + ldso[e]);
    }
  };

  f32x4 acc[4][4] = {};
  const int kbeg = kz * 1536, kend = kbeg + 1536;
  STAGE(0, kbeg);
  __syncthreads();
  int cur = 0;
  for (int k0 = kbeg; k0 < kend; k0 += 32) {
    if (k0 + 32 < kend) STAGE(cur ^ 1, k0 + 32);  // issue-early: hides under MFMA
    const char* L = lds + cur * 32768;
    h8 fah[4], fal[4], fbh[4], fbl[4];
#pragma unroll
    for (int i = 0; i < 4; ++i) {
      fah[i] = *(const h8*)(L + offA[i]);
      fal[i] = *(const h8*)(L + 8192 + offA[i]);
      fbh[i] = *(const h8*)(L + 16384 + offB[i]);
      fbl[i] = *(const h8*)(L + 24576 + offB[i]);
    }
#pragma unroll
    for (int i = 0; i < 4; ++i)
#pragma unroll
      for (int j = 0; j < 4; ++j)
        acc[i][j] = __builtin_amdgcn_mfma_f32_16x16x32_f16(fah[i], fbh[j], acc[i][j], 0, 0, 0);
#pragma unroll
    for (int i = 0; i < 4; ++i)
#pragma unroll
      for (int j = 0; j < 4; ++j)
        acc[i][j] = __builtin_amdgcn_mfma_f32_16x16x32_f16(fah[i], fbl[j], acc[i][j], 0, 0, 0);
#pragma unroll
    for (int i = 0; i < 4; ++i)
#pragma unroll
      for (int j = 0; j < 4; ++j)
        acc[i][j] = __builtin_amdgcn_mfma_f32_16x16x32_f16(fal[i], fbh[j], acc[i][j], 0, 0, 0);
    __syncthreads();
    cur ^= 1;
  }
  float* Pz = P + (size_t)kz * PSLAB;
  const int prow = (lane >> 4) * 4;
#pragma unroll
  for (int i = 0; i < 4; ++i) {
#pragma unroll
    for (int j = 0; j < 4; ++j) {
      int n = n0 + wn + j * 16 + lrow;
#pragma unroll
      for (int r2 = 0; r2 < 4; ++r2) {
        int m = m0 + wm + i * 16 + prow + r2;
        Pz[(size_t)m * 2048 + n] = acc[i][j][r2];
      }
    }
  }
}

// ---------------- nav_prep: fused split-K reduce -> rawh/rawl + rfeat mean --
// blocks [0,256): (g,chunk) compute relu rows, write h/l + column mean.
// blocks [256,260): zero pad rows 1568..1663.
__global__ __launch_bounds__(256) void nav_prep(const float* __restrict__ P,
                                                const float* __restrict__ bias,
                                                _Float16* __restrict__ h,
                                                _Float16* __restrict__ l,
                                                float* __restrict__ rfeat) {
  int b = blockIdx.x, t = threadIdx.x;
  if (b >= 256) {
    int b2 = b - 256;
    for (int i = t; i < 24 * 256; i += 256) {
      int row = 1568 + b2 * 24 + (i >> 8);
      int colq = (i & 255) * 8;
      h8 z = {};
      *(h8*)(h + (size_t)row * 2048 + colq) = z;
      *(h8*)(l + (size_t)row * 2048 + colq) = z;
    }
    return;
  }
  int g = b >> 5, chunk = b & 31;
  int col = chunk * 64 + (t & 63), rl = t >> 6;
  float bcol = bias[col];
  float s = 0.f;
  for (int r = rl; r < 196; r += 4) {
    size_t o = ((size_t)(g * 196 + r)) * 2048 + col;
    float v = fmaxf(fmaf(P[o] + P[PSLAB + o], RSCALE, bcol), 0.f);
    s += v;
    float sv = v * ASCALE;
    _Float16 a = (_Float16)sv;
    h[o] = a; l[o] = (_Float16)(sv - (float)a);
  }
  __shared__ float red[4][64];
  red[rl][t & 63] = s;
  __syncthreads();
  if (rl == 0) {
    int c = t & 63;
    rfeat[(size_t)g * 2048 + col] =
        ((red[0][c] + red[1][c]) + (red[2][c] + red[3][c])) / 196.0f;
  }
}

// ---------------- fused split-K reduce + relu + spatial mean (pfeat) --------
__global__ __launch_bounds__(256) void feat_reduce(const float* __restrict__ P,
                                                   const float* __restrict__ bias,
                                                   float* __restrict__ out,
                                                   int rows) {
  int g = blockIdx.x >> 5, chunk = blockIdx.x & 31;
  int col = chunk * 64 + (threadIdx.x & 63), rl = threadIdx.x >> 6;
  const float* base0 = P + ((size_t)g * rows) * 2048 + col;
  const float* base1 = base0 + PSLAB;
  float bcol = bias[col];
  float s = 0.f;
  for (int r = rl; r < rows; r += 4)
    s += fmaxf(fmaf(base0[(size_t)r * 2048] + base1[(size_t)r * 2048], RSCALE, bcol), 0.f);
  __shared__ float red[4][64];
  red[rl][threadIdx.x & 63] = s;
  __syncthreads();
  if (rl == 0) {
    int c = threadIdx.x & 63;
    out[(size_t)g * 2048 + col] =
        ((red[0][c] + red[1][c]) + (red[2][c] + red[3][c])) / (float)rows;
  }
}

// ---------------- navigator y1 GEMM: 64-row m-tiles, split-K=16, dbuf -------
// LDS 48KB (2 bufs x [Ah 4K|Al 4K|Bh 8K|Bl 8K]) -> 3 blocks/CU cap.
__global__ __launch_bounds__(256) void gemm_nav_mfma(
    const _Float16* __restrict__ Ah, const _Float16* __restrict__ Al,
    const _Float16* __restrict__ Bh, const _Float16* __restrict__ Bl,
    float* __restrict__ part) {
  __shared__ __align__(16) char lds[49152];
  const int t = threadIdx.x;
  // XCD-chunked bijective swizzle: 400 blocks = 8 XCD x 50 (m fastest per sp).
  const int bid = blockIdx.x;
  const int orig = (bid & 7) * 50 + (bid >> 3);
  const int m0 = (orig % 25) * 64;
  const int sp = orig / 25;  // 0..15
  const int lane = t & 63, w = t >> 6;
  const int wm = (w >> 1) * 32, wn = (w & 1) * 64;
  const int lrow = lane & 15, kg = lane >> 4;

  int offA[2], offB[4];
#pragma unroll
  for (int i = 0; i < 2; ++i) {
    int ba = (wm + i * 16 + lrow) * 64 + kg * 16;
    offA[i] = ba ^ (((ba >> 7) & 3) << 4);
  }
#pragma unroll
  for (int i = 0; i < 4; ++i) {
    int bb2 = (wn + i * 16 + lrow) * 64 + kg * 16;
    offB[i] = bb2 ^ (((bb2 >> 7) & 3) << 4);
  }
  // A staging source (single 4KB tile, 256 slots):
  int lslA = t ^ ((t >> 3) & 3);
  int rowA = lslA >> 2, kqA = lslA & 3;
  int mA = m0 + rowA;
  int amv = (mA < 1568);
  int ab = mA / 196, aps = mA % 196;
  int apy = aps / 14, apx = aps % 14;
  int akq8 = kqA * 8;
  int ldsoA = (t & 192) * 16;
  // B staging (8KB per tensor, 2 e's):
  size_t gBo[2];
  int ldsoB[2];
#pragma unroll
  for (int e = 0; e < 2; ++e) {
    int p = e * 256 + t;
    int lsl = p ^ ((p >> 3) & 3);
    int row = lsl >> 2, kq = lsl & 3;
    gBo[e] = (size_t)row * 18432 + kq * 8;
    ldsoB[e] = e * 4096 + (t & 192) * 16;
  }

  auto STAGE = [&](int buf, int k0) {
    const int tap = k0 >> 11;   // 32 | 2048: no tap straddle within a K-step
    const int c = k0 & 2047;
    const int dy = tap / 3 - 1, dx = tap % 3 - 1;
    char* L = lds + buf * 24576;
    int sy = apy + dy, sx = apx + dx;
    bool ok = amv && ((unsigned)sy < 14u) && ((unsigned)sx < 14u);
    size_t rowi = ok ? (size_t)(ab * 196 + sy * 14 + sx) : (size_t)1600;
    size_t ao = rowi * 2048 + c + akq8;
    gload16(Ah + ao, L + ldsoA);
    gload16(Al + ao, L + 4096 + ldsoA);
#pragma unroll
    for (int e = 0; e < 2; ++e) {
      gload16(Bh + gBo[e] + k0, L + 8192 + ldsoB[e]);
      gload16(Bl + gBo[e] + k0, L + 16384 + ldsoB[e]);
    }
  };

  f32x4 acc[2][4] = {};
  const int kbeg = sp * 1152, kend = kbeg + 1152;  // 36 K-steps
  STAGE(0, kbeg);
  __syncthreads();
  int cur = 0;
  for (int k0 = kbeg; k0 < kend; k0 += 32) {
    if (k0 + 32 < kend) STAGE(cur ^ 1, k0 + 32);
    const char* L = lds + cur * 24576;
    h8 fah[2], fal[2], fbh[4], fbl[4];
#pragma unroll
    for (int i = 0; i < 2; ++i) {
      fah[i] = *(const h8*)(L + offA[i]);
      fal[i] = *(const h8*)(L + 4096 + offA[i]);
    }
#pragma unroll
    for (int j = 0; j < 4; ++j) {
      fbh[j] = *(const h8*)(L + 8192 + offB[j]);
      fbl[j] = *(const h8*)(L + 16384 + offB[j]);
    }
#pragma unroll
    for (int i = 0; i < 2; ++i)
#pragma unroll
      for (int j = 0; j < 4; ++j)
        acc[i][j] = __builtin_amdgcn_mfma_f32_16x16x32_f16(fah[i], fbh[j], acc[i][j], 0, 0, 0);
#pragma unroll
    for (int i = 0; i < 2; ++i)
#pragma unroll
      for (int j = 0; j < 4; ++j)
        acc[i][j] = __builtin_amdgcn_mfma_f32_16x16x32_f16(fah[i], fbl[j], acc[i][j], 0, 0, 0);
#pragma unroll
    for (int i = 0; i < 2; ++i)
#pragma unroll
      for (int j = 0; j < 4; ++j)
        acc[i][j] = __builtin_amdgcn_mfma_f32_16x16x32_f16(fal[i], fbh[j], acc[i][j], 0, 0, 0);
    __syncthreads();
    cur ^= 1;
  }
  const int prow = (lane >> 4) * 4;
#pragma unroll
  for (int i = 0; i < 2; ++i) {
#pragma unroll
    for (int j = 0; j < 4; ++j) {
      int n = wn + j * 16 + lrow;
#pragma unroll
      for (int r = 0; r < 4; ++r) {
        int m = m0 + wm + i * 16 + prow + r;
        if (m < 1568)
          part[((size_t)sp * 1568 + m) * 128 + n] = acc[i][j][r] * RSCALE;
      }
    }
  }
}

__global__ __launch_bounds__(256) void y1_reduce(const float* __restrict__ part,
                                                 const float* __restrict__ b1,
                                                 float* __restrict__ y1) {
  int idx = blockIdx.x * 256 + threadIdx.x;   // over (1568*128)/4
  if (idx >= 1568 * 32) return;
  int o = (idx * 4) & 127;
  float4 s = *(const float4*)(b1 + o);
#pragma unroll
  for (int sp = 0; sp < 16; ++sp) {
    float4 v = *(const float4*)(part + (size_t)sp * 1568 * 128 + (size_t)idx * 4);
    s.x += v.x; s.y += v.y; s.z += v.z; s.w += v.w;
  }
  s.x = fmaxf(s.x, 0.f); s.y = fmaxf(s.y, 0.f);
  s.z = fmaxf(s.z, 0.f); s.w = fmaxf(s.w, 0.f);
  *(float4*)(y1 + (size_t)idx * 4) = s;
}

// ---------------- small 3x3 stride-2 pad-1 convs (128->128 ch, NHWC) --------
__global__ __launch_bounds__(256) void conv3x3s2(const float* __restrict__ in,
                                                 const float* __restrict__ wp,
                                                 const float* __restrict__ bias,
                                                 float* __restrict__ out,
                                                 int Hin, int Hout) {
  int idx = blockIdx.x * 256 + threadIdx.x;
  int total = 8 * Hout * Hout * 128;
  if (idx >= total) return;
  int o = idx & 127; int pos = idx >> 7;
  int ox = pos % Hout; int t2 = pos / Hout; int oy = t2 % Hout; int b = t2 / Hout;
  float acc = bias[o];
  for (int dy = 0; dy < 3; ++dy) {
    int iy = 2 * oy - 1 + dy;
    if (iy < 0 || iy >= Hin) continue;
    for (int dx = 0; dx < 3; ++dx) {
      int ix = 2 * ox - 1 + dx;
      if (ix < 0 || ix >= Hin) continue;
      const float* ip = in + ((b * Hin + iy) * Hin + ix) * 128;
      const float* wgt = wp + (o * 9 + dy * 3 + dx) * 128;
#pragma unroll 4
      for (int c = 0; c < 128; c += 4) {
        float4 a = *(const float4*)(ip + c);
        float4 ww = *(const float4*)(wgt + c);
        acc += a.x * ww.x + a.y * ww.y + a.z * ww.z + a.w * ww.w;
      }
    }
  }
  out[idx] = fmaxf(acc, 0.f);
}

// ---------------- rpn scores ------------------------------------------------
__global__ __launch_bounds__(256) void scores_kernel(
    const float* __restrict__ y1, const float* __restrict__ y2,
    const float* __restrict__ y3, const float* __restrict__ t1w,
    const float* __restrict__ t1b, const float* __restrict__ t2w,
    const float* __restrict__ t2b, const float* __restrict__ t3w,
    const float* __restrict__ t3b, float* __restrict__ scores) {
  int idx = blockIdx.x * 256 + threadIdx.x;
  if (idx >= 8 * 1614) return;
  int b = idx / 1614, sI = idx % 1614;
  const float* f; const float* w; float bias;
  if (sI < 1176) {
    int a = sI / 196;
    f = y1 + (b * 196 + (sI % 196)) * 128; w = t1w + a * 128; bias = t1b[a];
  } else if (sI < 1470) {
    int r = sI - 1176; int a = r / 49;
    f = y2 + (b * 49 + (r % 49)) * 128; w = t2w + a * 128; bias = t2b[a];
  } else {
    int r = sI - 1470; int a = r / 16;
    f = y3 + (b * 16 + (r % 16)) * 128; w = t3w + a * 128; bias = t3b[a];
  }
  float acc = 0.f;
  for (int c = 0; c < 128; c += 4) {
    float4 a4 = *(const float4*)(f + c);
    float4 w4 = *(const float4*)(w + c);
    acc += a4.x * w4.x + a4.y * w4.y + a4.z * w4.z + a4.w * w4.w;
  }
  scores[idx] = acc + bias;
}

// ---------------- greedy NMS (per batch block, wave-shuffle argmax) ---------
__global__ __launch_bounds__(256) void nms_kernel(const float* __restrict__ scores,
                                                  const int* __restrict__ anch,
                                                  const float* __restrict__ areas,
                                                  int* __restrict__ boxes) {
  const int b = blockIdx.x, t = threadIdx.x;
  const int lane = t & 63, wid = t >> 6;
  const float* s = scores + b * 1614;
  __shared__ unsigned char valid[1614];
  __shared__ float wv[4];
  __shared__ int wi[4];
  __shared__ int ssel;
  for (int i = t; i < 1614; i += 256) valid[i] = 1;
  __syncthreads();
  for (int n = 0; n < 4; ++n) {
    float best = -INFINITY; int bi = 0x7fffffff;
    for (int i = t; i < 1614; i += 256) {
      if (valid[i]) {
        float v = s[i];
        if (v > best || (v == best && i < bi)) { best = v; bi = i; }
      }
    }
#pragma unroll
    for (int off = 32; off > 0; off >>= 1) {
      float ov = __shfl_down(best, off, 64);
      int oi = __shfl_down(bi, off, 64);
      if (ov > best || (ov == best && oi < bi)) { best = ov; bi = oi; }
    }
    if (lane == 0) { wv[wid] = best; wi[wid] = bi; }
    __syncthreads();
    if (t == 0) {
      float bv = wv[0]; int bj = wi[0];
#pragma unroll
      for (int q = 1; q < 4; ++q)
        if (wv[q] > bv || (wv[q] == bv && wi[q] < bj)) { bv = wv[q]; bj = wi[q]; }
      if (bj > 1613) bj = 0;  // all-suppressed fallback
      ssel = bj;
      ((int4*)boxes)[b * 4 + n] = ((const int4*)anch)[bj];
    }
    __syncthreads();
    int sel = ssel;
    const int4 bb = ((const int4*)anch)[sel];
    const float Ai = areas[sel];
    for (int i = t; i < 1614; i += 256) {
      if (!valid[i]) continue;
      const int4 ab = ((const int4*)anch)[i];
      float sy = fmaxf((float)ab.x, (float)bb.x);
      float sx = fmaxf((float)ab.y, (float)bb.y);
      float ey = fminf((float)ab.z, (float)bb.z);
      float ex = fminf((float)ab.w, (float)bb.w);
      float ly = ey - sy, lx = ex - sx;
      float inter = (ly < 0.f || lx < 0.f) ? 0.f : ly * lx;
      float iou = inter / (areas[i] + Ai - inter);
      if (iou >= 0.25f) valid[i] = 0;
    }
    __syncthreads();
  }
}

// ---------------- bilinear crop -> A hi/lo (8-px vectorized, h8 writes) -----
__global__ __launch_bounds__(256) void crop_kernel(const float* __restrict__ x,
                                                   const int* __restrict__ boxes,
                                                   _Float16* __restrict__ Ah,
                                                   _Float16* __restrict__ Al) {
  int idx = blockIdx.x * 256 + threadIdx.x;   // over 32*3*224*28
  if (idx >= 32 * 3 * 224 * 28) return;
  int pxq = idx % 28; int t1 = idx / 28; int py = t1 % 224; int t2 = t1 / 224;
  int c = t2 % 3; int p = t2 / 3;
  int b = p >> 2;
  int px0 = pxq * 8;
  const int4 bb = ((const int4*)boxes)[p];
  float ty = (float)py / 223.0f;
  float ys = (float)bb.x + ty * (float)(bb.z - bb.x - 1);
  float yf = floorf(ys);
  float wy = ys - yf;
  int yl = (int)yf;
  int yh = min(yl + 1, 895);
  const float* img = x + (size_t)(b * 3 + c) * 448 * 448;
  auto samp = [&](int yy, int xx) -> float {
    yy -= 224; xx -= 224;
    if (yy < 0 || yy >= 448 || xx < 0 || xx >= 448) return 0.f;
    return img[yy * 448 + xx];
  };
  h8 vh, vl;
#pragma unroll
  for (int q = 0; q < 8; ++q) {
    int px = px0 + q;
    float txf = (float)px / 223.0f;
    float xs = (float)bb.y + txf * (float)(bb.w - bb.y - 1);
    float xf = floorf(xs);
    float wx = xs - xf;
    int xl = (int)xf;
    int xh = min(xl + 1, 895);
    float v00 = samp(yl, xl), v01 = samp(yl, xh);
    float v10 = samp(yh, xl), v11 = samp(yh, xh);
    float top = v00 * (1.f - wx) + v01 * wx;
    float bot = v10 * (1.f - wx) + v11 * wx;
    float val = top * (1.f - wy) + bot * wy;
    float sv = val * ASCALE;
    _Float16 a = (_Float16)sv;
    vh[q] = a; vl[q] = (_Float16)(sv - (float)a);
  }
  int i = py >> 5, r = py & 31, j = px0 >> 5, col = px0 & 31;
  int m = p * 49 + i * 7 + j;
  int k = (c << 10) + (r << 5) + col;
  *(h8*)(Ah + (size_t)m * 3072 + k) = vh;
  *(h8*)(Al + (size_t)m * 3072 + k) = vl;
}

// ---------------- final linear: one wave per (b, class) ---------------------
__global__ __launch_bounds__(256) void final_kernel(const float* __restrict__ pfeat,
                                                    const float* __restrict__ rfeat,
                                                    const float* __restrict__ cw,
                                                    const float* __restrict__ cb,
                                                    float* __restrict__ out) {
  int gw = (blockIdx.x * 256 + threadIdx.x) >> 6;
  int lane = threadIdx.x & 63;
  if (gw >= 1600) return;
  int b = gw / 200, j = gw % 200;
  const float* wr = cw + (size_t)j * 10240;
  const float* pf = pfeat + (size_t)b * 8192;
  float acc = 0.f;
  for (int k = lane * 4; k < 8192; k += 256) {
    float4 a = *(const float4*)(pf + k);
    float4 w = *(const float4*)(wr + k);
    acc += a.x * w.x + a.y * w.y + a.z * w.z + a.w * w.w;
  }
  const float* rf = rfeat + (size_t)b * 2048;
  const float* wr2 = wr + 8192;
  for (int k = lane * 4; k < 2048; k += 256) {
    float4 a = *(const float4*)(rf + k);
    float4 w = *(const float4*)(wr2 + k);
    acc += a.x * w.x + a.y * w.y + a.z * w.z + a.w * w.w;
  }
#pragma unroll
  for (int off = 32; off > 0; off >>= 1) acc += __shfl_down(acc, off, 64);
  if (lane == 0) out[b * 200 + j] = acc + cb[j];
}

// ---------------------------------------------------------------------------
extern "C" void kernel_launch(void* const* d_in, const int* in_sizes, int n_in,
                              void* d_out, int out_size, void* d_ws, size_t ws_size,
                              hipStream_t stream) {
  const float* x   = (const float*)d_in[0];
  const float* bbw = (const float*)d_in[1];
  const float* bbb = (const float*)d_in[2];
  const float* w1  = (const float*)d_in[3];
  const float* b1  = (const float*)d_in[4];
  const float* t1w = (const float*)d_in[5];
  const float* t1b = (const float*)d_in[6];
  const float* w2  = (const float*)d_in[7];
  const float* b2  = (const float*)d_in[8];
  const float* t2w = (const float*)d_in[9];
  const float* t2b = (const float*)d_in[10];
  const float* w3  = (const float*)d_in[11];
  const float* b3  = (const float*)d_in[12];
  const float* t3w = (const float*)d_in[13];
  const float* t3b = (const float*)d_in[14];
  const float* cw  = (const float*)d_in[15];
  const float* cb  = (const float*)d_in[16];
  float* out = (float*)d_out;

  char* p = (char*)d_ws;
  auto alloc = [&](size_t bytes) -> char* {
    char* r = p; p += (bytes + 255) & ~(size_t)255; return r;
  };
  int*      anch  = (int*)     alloc((size_t)1614 * 4 * 4);
  float*    areas = (float*)   alloc((size_t)1614 * 4);
  _Float16* bWh   = (_Float16*)alloc((size_t)2048 * 3072 * 2);
  _Float16* bWl   = (_Float16*)alloc((size_t)2048 * 3072 * 2);
  _Float16* w1h   = (_Float16*)alloc((size_t)128 * 18432 * 2);
  _Float16* w1l   = (_Float16*)alloc((size_t)128 * 18432 * 2);
  _Float16* Ahh   = (_Float16*)alloc((size_t)1664 * 3072 * 2);
  _Float16* All   = (_Float16*)alloc((size_t)1664 * 3072 * 2);
  _Float16* rawh  = (_Float16*)alloc((size_t)1664 * 2048 * 2);
  _Float16* rawl  = (_Float16*)alloc((size_t)1664 * 2048 * 2);
  float*    w2p   = (float*)   alloc((size_t)128 * 9 * 128 * 4);
  float*    w3p   = (float*)   alloc((size_t)128 * 9 * 128 * 4);
  // P (split-K=2 partials) aliases y1s (16x1568x128 f32): disjoint lifetimes.
  char*     big   = alloc((size_t)2 * PSLAB * 4);
  float*    Pbuf  = (float*)big;
  float*    y1s   = (float*)big;
  float*    y1v   = (float*)   alloc((size_t)1568 * 128 * 4);
  float*    y2v   = (float*)   alloc((size_t)392 * 128 * 4);
  float*    y3v   = (float*)   alloc((size_t)128 * 128 * 4);
  float*    sc    = (float*)   alloc((size_t)8 * 1614 * 4);
  int*      boxes = (int*)     alloc((size_t)8 * 4 * 4 * 4);
  float*    pfeat = (float*)   alloc((size_t)32 * 2048 * 4);
  float*    rfeat = (float*)   alloc((size_t)8 * 2048 * 4);

  mega_prep<<<7239, 256, 0, stream>>>(anch, areas, w2, w2p, w3, w3p,
                                      bbw, bWh, bWl, w1, w1h, w1l, x, Ahh, All);

  gemm_bb_mfma<<<dim3(13, 16, 2), 256, 0, stream>>>(Ahh, All, bWh, bWl, Pbuf);
  nav_prep<<<260, 256, 0, stream>>>(Pbuf, bbb, rawh, rawl, rfeat);
  gemm_nav_mfma<<<400, 256, 0, stream>>>(rawh, rawl, w1h, w1l, y1s);
  y1_reduce<<<(1568 * 32 + 255) / 256, 256, 0, stream>>>(y1s, b1, y1v);
  conv3x3s2<<<(8 * 7 * 7 * 128 + 255) / 256, 256, 0, stream>>>(y1v, w2p, b2, y2v, 14, 7);
  conv3x3s2<<<(8 * 4 * 4 * 128 + 255) / 256, 256, 0, stream>>>(y2v, w3p, b3, y3v, 7, 4);
  scores_kernel<<<(8 * 1614 + 255) / 256, 256, 0, stream>>>(
      y1v, y2v, y3v, t1w, t1b, t2w, t2b, t3w, t3b, sc);
  nms_kernel<<<8, 256, 0, stream>>>(sc, anch, areas, boxes);
  crop_kernel<<<(32 * 3 * 224 * 28 + 255) / 256, 256, 0, stream>>>(x, boxes, Ahh, All);
  gemm_bb_mfma<<<dim3(13, 16, 2), 256, 0, stream>>>(Ahh, All, bWh, bWl, Pbuf);
  feat_reduce<<<32 * 32, 256, 0, stream>>>(Pbuf, bbb, pfeat, 49);
  final_kernel<<<400, 256, 0, stream>>>(pfeat, rfeat, cw, cb, out);
}